// Round 1
// baseline (4569.620 us; speedup 1.0000x reference)
//
#include <hip/hip_runtime.h>
#include <math.h>

#define NN 20000
#define EE 320000
#define DIN 64
#define HIDC 128
#define NH 4
#define NCOLS 1664   // 512 q | 512 k | 512 v | 128 skip
#define NL 3
#define ENC_NEG_INF 0x007FFFFFu  // orderable-uint encoding of -inf

__device__ __forceinline__ unsigned enc_f(float f) {
  unsigned b = __float_as_uint(f);
  return (b & 0x80000000u) ? ~b : (b ^ 0x80000000u);
}
__device__ __forceinline__ float dec_f(unsigned u) {
  unsigned b = (u & 0x80000000u) ? (u ^ 0x80000000u) : ~u;
  return __uint_as_float(b);
}

__global__ void build_wcat(const float* __restrict__ Wq, const float* __restrict__ Wk,
                           const float* __restrict__ Wv, const float* __restrict__ Wsk,
                           float* __restrict__ Wcat) {
  int idx = blockIdx.x * 256 + threadIdx.x;
  if (idx >= HIDC * NCOLS) return;
  int k = idx / NCOLS, m = idx - k * NCOLS;
  float v;
  if (m < 512)       v = Wq[k * 512 + m];
  else if (m < 1024) v = Wk[k * 512 + (m - 512)];
  else if (m < 1536) v = Wv[k * 512 + (m - 1024)];
  else               v = Wsk[k * 128 + (m - 1536)];
  Wcat[idx] = v;
}

__global__ void build_bcat(const float* __restrict__ bq, const float* __restrict__ bk,
                           const float* __restrict__ bv, const float* __restrict__ bsk,
                           float* __restrict__ bcat) {
  int m = blockIdx.x * 256 + threadIdx.x;
  if (m >= NCOLS) return;
  float v;
  if (m < 512)       v = bq[m];
  else if (m < 1024) v = bk[m - 512];
  else if (m < 1536) v = bv[m - 1024];
  else               v = bsk[m - 1536];
  bcat[m] = v;
}

__global__ void fill_u32(unsigned* __restrict__ p, unsigned v, int n) {
  int i = blockIdx.x * 256 + threadIdx.x;
  if (i < n) p[i] = v;
}

template <int K>
__global__ __launch_bounds__(256) void gemm_bias(
    const float* __restrict__ A, const float* __restrict__ W,
    const float* __restrict__ bias, float* __restrict__ C,
    int n_rows, int n_cols) {
  constexpr int AS = K + 4;
  __shared__ __align__(16) float As[64][AS];
  __shared__ __align__(16) float Ws[K][64];
  const int tid = threadIdx.x;
  const int row0 = blockIdx.y * 64;
  const int col0 = blockIdx.x * 64;
  constexpr int K4 = K / 4;
#pragma unroll
  for (int p = 0; p < (64 * K4) / 256; ++p) {
    int it = p * 256 + tid;
    int r = it / K4, c4 = it - r * K4;
    float4 v = make_float4(0.f, 0.f, 0.f, 0.f);
    if (row0 + r < n_rows) v = *(const float4*)(A + (size_t)(row0 + r) * K + c4 * 4);
    *(float4*)&As[r][c4 * 4] = v;
  }
#pragma unroll
  for (int p = 0; p < (K * 16) / 256; ++p) {
    int it = p * 256 + tid;
    int k = it / 16, c4 = it - k * 16;
    *(float4*)&Ws[k][c4 * 4] = *(const float4*)(W + (size_t)k * n_cols + col0 + c4 * 4);
  }
  __syncthreads();
  const int tx = tid & 15, ty = tid >> 4;
  float acc[4][4];
#pragma unroll
  for (int i = 0; i < 4; i++)
#pragma unroll
    for (int j = 0; j < 4; j++) acc[i][j] = 0.f;

  for (int k = 0; k < K; k += 4) {
    float4 a[4], w[4];
#pragma unroll
    for (int i = 0; i < 4; i++) a[i] = *(const float4*)&As[ty * 4 + i][k];
#pragma unroll
    for (int kk = 0; kk < 4; kk++) w[kk] = *(const float4*)&Ws[k + kk][tx * 4];
#pragma unroll
    for (int i = 0; i < 4; i++) {
      const float av[4] = {a[i].x, a[i].y, a[i].z, a[i].w};
#pragma unroll
      for (int kk = 0; kk < 4; kk++) {
        acc[i][0] += av[kk] * w[kk].x;
        acc[i][1] += av[kk] * w[kk].y;
        acc[i][2] += av[kk] * w[kk].z;
        acc[i][3] += av[kk] * w[kk].w;
      }
    }
  }
#pragma unroll
  for (int i = 0; i < 4; i++) {
    int r = row0 + ty * 4 + i;
    if (r < n_rows) {
      int c = col0 + tx * 4;
      float4 b4 = *(const float4*)(bias + c);
      float4 o = make_float4(acc[i][0] + b4.x, acc[i][1] + b4.y,
                             acc[i][2] + b4.z, acc[i][3] + b4.w);
      *(float4*)(C + (size_t)r * n_cols + c) = o;
    }
  }
}

__global__ __launch_bounds__(256) void edge_logits(
    const float* __restrict__ qkvs, const int* __restrict__ ei,
    float* __restrict__ logits, unsigned* __restrict__ mbuf) {
  int e = blockIdx.x * 4 + (threadIdx.x >> 6);
  if (e >= EE) return;
  int lane = threadIdx.x & 63;
  int hh = lane >> 4, t = lane & 15;
  int src = ei[e], dst = ei[EE + e];
  const float4* qp = (const float4*)(qkvs + (size_t)dst * NCOLS + hh * 128 + t * 8);
  const float4* kp = (const float4*)(qkvs + (size_t)src * NCOLS + 512 + hh * 128 + t * 8);
  float4 q0 = qp[0], q1 = qp[1];
  float4 k0 = kp[0], k1 = kp[1];
  float p = q0.x * k0.x + q0.y * k0.y + q0.z * k0.z + q0.w * k0.w +
            q1.x * k1.x + q1.y * k1.y + q1.z * k1.z + q1.w * k1.w;
  p += __shfl_xor(p, 1);
  p += __shfl_xor(p, 2);
  p += __shfl_xor(p, 4);
  p += __shfl_xor(p, 8);
  if (t == 0) {
    float lg = p * 0.08838834764831845f;
    logits[e * 4 + hh] = lg;
    atomicMax(mbuf + (size_t)dst * 4 + hh, enc_f(lg));
  }
}

__global__ void edge_exp(const int* __restrict__ ei, float* __restrict__ logits,
                         const unsigned* __restrict__ mbuf, float* __restrict__ sbuf) {
  int idx = blockIdx.x * 256 + threadIdx.x;
  if (idx >= EE * 4) return;
  int e = idx >> 2, hh = idx & 3;
  int dst = ei[EE + e];
  float mval = dec_f(mbuf[(size_t)dst * 4 + hh]);
  float ex = expf(logits[idx] - mval);
  logits[idx] = ex;
  atomicAdd(sbuf + (size_t)dst * 4 + hh, ex);
}

__global__ __launch_bounds__(256) void edge_aggr(
    const float* __restrict__ qkvs, const int* __restrict__ ei,
    const float* __restrict__ exv, const float* __restrict__ sbuf,
    float* __restrict__ aggr) {
  int e = blockIdx.x * 4 + (threadIdx.x >> 6);
  if (e >= EE) return;
  int lane = threadIdx.x & 63;
  int hh = lane >> 4, t = lane & 15;
  int src = ei[e], dst = ei[EE + e];
  float w = exv[e * 4 + hh] / (sbuf[(size_t)dst * 4 + hh] + 1e-16f) * 0.25f;
  const float4* vp = (const float4*)(qkvs + (size_t)src * NCOLS + 1024 + hh * 128 + t * 8);
  float4 v0 = vp[0], v1 = vp[1];
  float r[8] = {w * v0.x, w * v0.y, w * v0.z, w * v0.w,
                w * v1.x, w * v1.y, w * v1.z, w * v1.w};
#pragma unroll
  for (int j = 0; j < 8; j++) {
    r[j] += __shfl_xor(r[j], 16);
    r[j] += __shfl_xor(r[j], 32);
  }
  if (hh == 0) {
    float* op = aggr + (size_t)dst * 128 + t * 8;
#pragma unroll
    for (int j = 0; j < 8; j++) atomicAdd(op + j, r[j]);
  }
}

__global__ __launch_bounds__(256) void node_finalize(
    const float* __restrict__ h, const float* __restrict__ qkvs,
    const float* __restrict__ aggr, const float* __restrict__ gamma,
    const float* __restrict__ beta, float* __restrict__ outp) {
  int n = blockIdx.x * 4 + (threadIdx.x >> 6);
  if (n >= NN) return;
  int lane = threadIdx.x & 63;
  size_t hb = (size_t)n * 128;
  size_t qb = (size_t)n * NCOLS + 1536;
  float u0 = h[hb + lane] + aggr[hb + lane] + qkvs[qb + lane];
  float u1 = h[hb + lane + 64] + aggr[hb + lane + 64] + qkvs[qb + lane + 64];
  float ssum = u0 + u1;
#pragma unroll
  for (int d = 1; d < 64; d <<= 1) ssum += __shfl_xor(ssum, d);
  float mu = ssum * (1.f / 128.f);
  float d0 = u0 - mu, d1 = u1 - mu;
  float vs = d0 * d0 + d1 * d1;
#pragma unroll
  for (int d = 1; d < 64; d <<= 1) vs += __shfl_xor(vs, d);
  float inv = rsqrtf(vs * (1.f / 128.f) + 1e-5f);
  outp[hb + lane] = d0 * inv * gamma[lane] + beta[lane];
  outp[hb + lane + 64] = d1 * inv * gamma[lane + 64] + beta[lane + 64];
}

#define OFF_H      ((size_t)0)
#define OFF_QKVS   ((size_t)2560000)
#define OFF_WCAT   ((size_t)35840000)
#define OFF_BCAT   ((size_t)36052992)
#define OFF_LOGIT  ((size_t)36054656)
#define OFF_M      ((size_t)37334656)
#define OFF_S      ((size_t)37414656)
#define OFF_AGGR   ((size_t)37494656)

extern "C" void kernel_launch(void* const* d_in, const int* in_sizes, int n_in,
                              void* d_out, int out_size, void* d_ws, size_t ws_size,
                              hipStream_t stream) {
  const float* x    = (const float*)d_in[0];
  const int*   ei   = (const int*)d_in[1];
  const float* Win  = (const float*)d_in[2];
  const float* bin_ = (const float*)d_in[3];
  const float* Wq   = (const float*)d_in[4];
  const float* bq   = (const float*)d_in[5];
  const float* Wk   = (const float*)d_in[6];
  const float* bk   = (const float*)d_in[7];
  const float* Wv   = (const float*)d_in[8];
  const float* bv   = (const float*)d_in[9];
  const float* Wsk  = (const float*)d_in[10];
  const float* bsk  = (const float*)d_in[11];
  const float* lng  = (const float*)d_in[12];
  const float* lnb  = (const float*)d_in[13];
  float* out = (float*)d_out;
  float* ws = (float*)d_ws;

  float* h     = ws + OFF_H;
  float* qkvs  = ws + OFF_QKVS;
  float* Wcat  = ws + OFF_WCAT;
  float* bcat  = ws + OFF_BCAT;
  float* logit = ws + OFF_LOGIT;
  unsigned* mb = (unsigned*)(ws + OFF_M);
  float* sb    = ws + OFF_S;
  float* aggr  = ws + OFF_AGGR;

  {
    dim3 g(HIDC / 64, (NN + 63) / 64);
    gemm_bias<DIN><<<g, 256, 0, stream>>>(x, Win, bin_, h, NN, HIDC);
  }

  for (int l = 0; l < NL; ++l) {
    build_wcat<<<(HIDC * NCOLS + 255) / 256, 256, 0, stream>>>(
        Wq + (size_t)l * HIDC * 512, Wk + (size_t)l * HIDC * 512,
        Wv + (size_t)l * HIDC * 512, Wsk + (size_t)l * HIDC * HIDC, Wcat);
    build_bcat<<<(NCOLS + 255) / 256, 256, 0, stream>>>(
        bq + (size_t)l * 512, bk + (size_t)l * 512, bv + (size_t)l * 512,
        bsk + (size_t)l * 128, bcat);

    {
      dim3 g(NCOLS / 64, (NN + 63) / 64);
      gemm_bias<HIDC><<<g, 256, 0, stream>>>(h, Wcat, bcat, qkvs, NN, NCOLS);
    }

    fill_u32<<<(NN * 4 + 255) / 256, 256, 0, stream>>>(mb, ENC_NEG_INF, NN * 4);
    hipMemsetAsync(sb, 0, (size_t)NN * 4 * sizeof(float), stream);
    hipMemsetAsync(aggr, 0, (size_t)NN * 128 * sizeof(float), stream);

    edge_logits<<<(EE + 3) / 4, 256, 0, stream>>>(qkvs, ei, logit, mb);
    edge_exp<<<(EE * 4 + 255) / 256, 256, 0, stream>>>(ei, logit, mb, sb);
    edge_aggr<<<(EE + 3) / 4, 256, 0, stream>>>(qkvs, ei, logit, sb, aggr);

    float* dst = (l == NL - 1) ? out : h;
    node_finalize<<<(NN + 3) / 4, 256, 0, stream>>>(
        h, qkvs, aggr, lng + (size_t)l * 128, lnb + (size_t)l * 128, dst);
  }
  (void)in_sizes; (void)n_in; (void)out_size; (void)ws_size;
}

// Round 2
// 1122.084 us; speedup vs baseline: 4.0724x; 4.0724x over previous
//
#include <hip/hip_runtime.h>
#include <math.h>

#define NN 20000
#define EE 320000
#define DIN 64
#define HIDC 128
#define NCOLS 1664   // 512 q | 512 k | 512 v | 128 skip
#define NL 3

// ---------------- weight/bias concat ----------------
__global__ void build_wcat(const float* __restrict__ Wq, const float* __restrict__ Wk,
                           const float* __restrict__ Wv, const float* __restrict__ Wsk,
                           float* __restrict__ Wcat) {
  int idx = blockIdx.x * 256 + threadIdx.x;
  if (idx >= HIDC * NCOLS) return;
  int k = idx / NCOLS, m = idx - k * NCOLS;
  float v;
  if (m < 512)       v = Wq[k * 512 + m];
  else if (m < 1024) v = Wk[k * 512 + (m - 512)];
  else if (m < 1536) v = Wv[k * 512 + (m - 1024)];
  else               v = Wsk[k * 128 + (m - 1536)];
  Wcat[idx] = v;
}

__global__ void build_bcat(const float* __restrict__ bq, const float* __restrict__ bk,
                           const float* __restrict__ bv, const float* __restrict__ bsk,
                           float* __restrict__ bcat) {
  int m = blockIdx.x * 256 + threadIdx.x;
  if (m >= NCOLS) return;
  float v;
  if (m < 512)       v = bq[m];
  else if (m < 1024) v = bk[m - 512];
  else if (m < 1536) v = bv[m - 1024];
  else               v = bsk[m - 1536];
  bcat[m] = v;
}

// ---------------- CSR build ----------------
__global__ void deg_hist(const int* __restrict__ ei, int* __restrict__ deg) {
  int e = blockIdx.x * 256 + threadIdx.x;
  if (e >= EE) return;
  atomicAdd(&deg[ei[EE + e]], 1);
}

__global__ __launch_bounds__(1024) void scan_deg(const int* __restrict__ deg,
                                                 int* __restrict__ rowstart) {
  __shared__ int part[1024];
  int t = threadIdx.x;
  int base = t * 20;
  int local[20];
  int s = 0;
#pragma unroll
  for (int i = 0; i < 20; i++) {
    int idx = base + i;
    int d = (idx < NN) ? deg[idx] : 0;
    local[i] = d;
    s += d;
  }
  part[t] = s;
  __syncthreads();
  for (int d = 1; d < 1024; d <<= 1) {
    int v = (t >= d) ? part[t - d] : 0;
    __syncthreads();
    part[t] += v;
    __syncthreads();
  }
  int run = part[t] - s;  // exclusive prefix of this thread's chunk
#pragma unroll
  for (int i = 0; i < 20; i++) {
    int idx = base + i;
    if (idx < NN) rowstart[idx] = run;
    run += local[i];
  }
  if (t == 1023) rowstart[NN] = part[1023];
}

__global__ void csr_scatter(const int* __restrict__ ei, const int* __restrict__ rowstart,
                            int* __restrict__ cur, int* __restrict__ csr) {
  int e = blockIdx.x * 256 + threadIdx.x;
  if (e >= EE) return;
  int dst = ei[EE + e];
  int pos = atomicAdd(&cur[dst], 1);
  csr[rowstart[dst] + pos] = e;
}

// ---------------- fp32 tiled GEMM ----------------
template <int K>
__global__ __launch_bounds__(256) void gemm_bias(
    const float* __restrict__ A, const float* __restrict__ W,
    const float* __restrict__ bias, float* __restrict__ C,
    int n_rows, int n_cols) {
  constexpr int AS = K + 4;
  __shared__ __align__(16) float As[64][AS];
  __shared__ __align__(16) float Ws[K][64];
  const int tid = threadIdx.x;
  const int row0 = blockIdx.y * 64;
  const int col0 = blockIdx.x * 64;
  constexpr int K4 = K / 4;
#pragma unroll
  for (int p = 0; p < (64 * K4) / 256; ++p) {
    int it = p * 256 + tid;
    int r = it / K4, c4 = it - r * K4;
    float4 v = make_float4(0.f, 0.f, 0.f, 0.f);
    if (row0 + r < n_rows) v = *(const float4*)(A + (size_t)(row0 + r) * K + c4 * 4);
    *(float4*)&As[r][c4 * 4] = v;
  }
#pragma unroll
  for (int p = 0; p < (K * 16) / 256; ++p) {
    int it = p * 256 + tid;
    int k = it / 16, c4 = it - k * 16;
    *(float4*)&Ws[k][c4 * 4] = *(const float4*)(W + (size_t)k * n_cols + col0 + c4 * 4);
  }
  __syncthreads();
  const int tx = tid & 15, ty = tid >> 4;
  float acc[4][4];
#pragma unroll
  for (int i = 0; i < 4; i++)
#pragma unroll
    for (int j = 0; j < 4; j++) acc[i][j] = 0.f;

  for (int k = 0; k < K; k += 4) {
    float4 a[4], w[4];
#pragma unroll
    for (int i = 0; i < 4; i++) a[i] = *(const float4*)&As[ty * 4 + i][k];
#pragma unroll
    for (int kk = 0; kk < 4; kk++) w[kk] = *(const float4*)&Ws[k + kk][tx * 4];
#pragma unroll
    for (int i = 0; i < 4; i++) {
      const float av[4] = {a[i].x, a[i].y, a[i].z, a[i].w};
#pragma unroll
      for (int kk = 0; kk < 4; kk++) {
        acc[i][0] += av[kk] * w[kk].x;
        acc[i][1] += av[kk] * w[kk].y;
        acc[i][2] += av[kk] * w[kk].z;
        acc[i][3] += av[kk] * w[kk].w;
      }
    }
  }
#pragma unroll
  for (int i = 0; i < 4; i++) {
    int r = row0 + ty * 4 + i;
    if (r < n_rows) {
      int c = col0 + tx * 4;
      float4 b4 = *(const float4*)(bias + c);
      float4 o = make_float4(acc[i][0] + b4.x, acc[i][1] + b4.y,
                             acc[i][2] + b4.z, acc[i][3] + b4.w);
      *(float4*)(C + (size_t)r * n_cols + c) = o;
    }
  }
}

// ---------------- edge logits (CSR-ordered, no atomics) ----------------
__global__ __launch_bounds__(256) void edge_logits_csr(
    const float* __restrict__ qkvs, const int* __restrict__ ei,
    const int* __restrict__ csr, float* __restrict__ logc,
    int* __restrict__ csrc) {
  int j = blockIdx.x * 4 + (threadIdx.x >> 6);
  if (j >= EE) return;
  int lane = threadIdx.x & 63;
  int hh = lane >> 4, t = lane & 15;
  int e = csr[j];
  int src = ei[e], dst = ei[EE + e];
  const float4* qp = (const float4*)(qkvs + (size_t)dst * NCOLS + hh * 128 + t * 8);
  const float4* kp = (const float4*)(qkvs + (size_t)src * NCOLS + 512 + hh * 128 + t * 8);
  float4 q0 = qp[0], q1 = qp[1];
  float4 k0 = kp[0], k1 = kp[1];
  float p = q0.x * k0.x + q0.y * k0.y + q0.z * k0.z + q0.w * k0.w +
            q1.x * k1.x + q1.y * k1.y + q1.z * k1.z + q1.w * k1.w;
  p += __shfl_xor(p, 1);
  p += __shfl_xor(p, 2);
  p += __shfl_xor(p, 4);
  p += __shfl_xor(p, 8);
  if (t == 0) logc[j * 4 + hh] = p * 0.08838834764831845f;  // 1/sqrt(128)
  if (lane == 0) csrc[j] = src;
}

// ---------------- node aggregation + skip + residual + LN (no atomics) ----------------
__global__ __launch_bounds__(256) void node_aggr_ln(
    const float* __restrict__ qkvs, const float* __restrict__ h,
    const int* __restrict__ rowstart, const int* __restrict__ csrc,
    const float* __restrict__ logc, const float* __restrict__ gamma,
    const float* __restrict__ beta, float* __restrict__ outp) {
  int n = blockIdx.x * 4 + (threadIdx.x >> 6);
  if (n >= NN) return;
  int lane = threadIdx.x & 63;
  int j0 = rowstart[n], j1 = rowstart[n + 1];

  // pass A: online softmax stats, lanes parallel over edges
  float m0 = -INFINITY, m1 = -INFINITY, m2 = -INFINITY, m3 = -INFINITY;
  float s0 = 0.f, s1 = 0.f, s2 = 0.f, s3 = 0.f;
  for (int j = j0 + lane; j < j1; j += 64) {
    float4 lg = *(const float4*)(logc + (size_t)j * 4);
    float nm;
    nm = fmaxf(m0, lg.x); s0 = s0 * expf(m0 - nm) + expf(lg.x - nm); m0 = nm;
    nm = fmaxf(m1, lg.y); s1 = s1 * expf(m1 - nm) + expf(lg.y - nm); m1 = nm;
    nm = fmaxf(m2, lg.z); s2 = s2 * expf(m2 - nm) + expf(lg.z - nm); m2 = nm;
    nm = fmaxf(m3, lg.w); s3 = s3 * expf(m3 - nm) + expf(lg.w - nm); m3 = nm;
  }
  // reduce max across lanes
  float M0 = m0, M1 = m1, M2 = m2, M3 = m3;
#pragma unroll
  for (int d = 1; d < 64; d <<= 1) {
    M0 = fmaxf(M0, __shfl_xor(M0, d));
    M1 = fmaxf(M1, __shfl_xor(M1, d));
    M2 = fmaxf(M2, __shfl_xor(M2, d));
    M3 = fmaxf(M3, __shfl_xor(M3, d));
  }
  // rescale partial sums to global max, reduce
  float S0 = (s0 > 0.f) ? s0 * expf(m0 - M0) : 0.f;
  float S1 = (s1 > 0.f) ? s1 * expf(m1 - M1) : 0.f;
  float S2 = (s2 > 0.f) ? s2 * expf(m2 - M2) : 0.f;
  float S3 = (s3 > 0.f) ? s3 * expf(m3 - M3) : 0.f;
#pragma unroll
  for (int d = 1; d < 64; d <<= 1) {
    S0 += __shfl_xor(S0, d);
    S1 += __shfl_xor(S1, d);
    S2 += __shfl_xor(S2, d);
    S3 += __shfl_xor(S3, d);
  }
  float r0 = 0.25f / (S0 + 1e-16f);
  float r1 = 0.25f / (S1 + 1e-16f);
  float r2 = 0.25f / (S2 + 1e-16f);
  float r3 = 0.25f / (S3 + 1e-16f);

  // pass B: weighted V gather-accumulate (serial over edges, lanes = dims)
  float acc0 = 0.f, acc1 = 0.f;
  for (int j = j0; j < j1; ++j) {
    int src = csrc[j];
    float4 lg = *(const float4*)(logc + (size_t)j * 4);
    float w0 = expf(lg.x - M0) * r0;
    float w1 = expf(lg.y - M1) * r1;
    float w2 = expf(lg.z - M2) * r2;
    float w3 = expf(lg.w - M3) * r3;
    const float* vb = qkvs + (size_t)src * NCOLS + 1024;
    acc0 += w0 * vb[lane]       + w1 * vb[128 + lane] +
            w2 * vb[256 + lane] + w3 * vb[384 + lane];
    acc1 += w0 * vb[64 + lane]  + w1 * vb[192 + lane] +
            w2 * vb[320 + lane] + w3 * vb[448 + lane];
  }

  // finalize: h + aggr + skip, then LayerNorm
  size_t hb = (size_t)n * 128;
  size_t qb = (size_t)n * NCOLS + 1536;
  float u0 = h[hb + lane]      + acc0 + qkvs[qb + lane];
  float u1 = h[hb + lane + 64] + acc1 + qkvs[qb + lane + 64];
  float ssum = u0 + u1;
#pragma unroll
  for (int d = 1; d < 64; d <<= 1) ssum += __shfl_xor(ssum, d);
  float mu = ssum * (1.f / 128.f);
  float d0 = u0 - mu, d1 = u1 - mu;
  float vs = d0 * d0 + d1 * d1;
#pragma unroll
  for (int d = 1; d < 64; d <<= 1) vs += __shfl_xor(vs, d);
  float inv = rsqrtf(vs * (1.f / 128.f) + 1e-5f);
  outp[hb + lane]      = d0 * inv * gamma[lane] + beta[lane];
  outp[hb + lane + 64] = d1 * inv * gamma[lane + 64] + beta[lane + 64];
}

// ---------------- workspace layout (float offsets) ----------------
#define OFF_H      ((size_t)0)           // N*128      = 2,560,000
#define OFF_QKVS   ((size_t)2560000)     // N*1664     = 33,280,000
#define OFF_WCAT   ((size_t)35840000)    // 128*1664   = 212,992
#define OFF_BCAT   ((size_t)36052992)    // 1664
#define OFF_LOGC   ((size_t)36054656)    // E*4        = 1,280,000
#define OFF_CSR    ((size_t)37334656)    // E ints
#define OFF_SRC    ((size_t)37654656)    // E ints
#define OFF_ROW    ((size_t)37974656)    // N+1 ints
#define OFF_DEG    ((size_t)37994660)    // N ints
#define OFF_CUR    ((size_t)38014660)    // N ints
// total 38,034,660 floats ≈ 152.1 MB

extern "C" void kernel_launch(void* const* d_in, const int* in_sizes, int n_in,
                              void* d_out, int out_size, void* d_ws, size_t ws_size,
                              hipStream_t stream) {
  const float* x    = (const float*)d_in[0];
  const int*   ei   = (const int*)d_in[1];
  const float* Win  = (const float*)d_in[2];
  const float* bin_ = (const float*)d_in[3];
  const float* Wq   = (const float*)d_in[4];
  const float* bq   = (const float*)d_in[5];
  const float* Wk   = (const float*)d_in[6];
  const float* bk   = (const float*)d_in[7];
  const float* Wv   = (const float*)d_in[8];
  const float* bv   = (const float*)d_in[9];
  const float* Wsk  = (const float*)d_in[10];
  const float* bsk  = (const float*)d_in[11];
  const float* lng  = (const float*)d_in[12];
  const float* lnb  = (const float*)d_in[13];
  float* out = (float*)d_out;
  float* ws = (float*)d_ws;

  float* h     = ws + OFF_H;
  float* qkvs  = ws + OFF_QKVS;
  float* Wcat  = ws + OFF_WCAT;
  float* bcat  = ws + OFF_BCAT;
  float* logc  = ws + OFF_LOGC;
  int* csr      = (int*)(ws + OFF_CSR);
  int* csrc     = (int*)(ws + OFF_SRC);
  int* rowstart = (int*)(ws + OFF_ROW);
  int* deg      = (int*)(ws + OFF_DEG);
  int* cur      = (int*)(ws + OFF_CUR);

  // ---- CSR build (once; edge_index constant) ----
  hipMemsetAsync(deg, 0, NN * sizeof(int), stream);
  hipMemsetAsync(cur, 0, NN * sizeof(int), stream);
  deg_hist<<<(EE + 255) / 256, 256, 0, stream>>>(ei, deg);
  scan_deg<<<1, 1024, 0, stream>>>(deg, rowstart);
  csr_scatter<<<(EE + 255) / 256, 256, 0, stream>>>(ei, rowstart, cur, csr);

  // ---- input projection ----
  {
    dim3 g(HIDC / 64, (NN + 63) / 64);
    gemm_bias<DIN><<<g, 256, 0, stream>>>(x, Win, bin_, h, NN, HIDC);
  }

  for (int l = 0; l < NL; ++l) {
    build_wcat<<<(HIDC * NCOLS + 255) / 256, 256, 0, stream>>>(
        Wq + (size_t)l * HIDC * 512, Wk + (size_t)l * HIDC * 512,
        Wv + (size_t)l * HIDC * 512, Wsk + (size_t)l * HIDC * HIDC, Wcat);
    build_bcat<<<(NCOLS + 255) / 256, 256, 0, stream>>>(
        bq + (size_t)l * 512, bk + (size_t)l * 512, bv + (size_t)l * 512,
        bsk + (size_t)l * 128, bcat);

    {
      dim3 g(NCOLS / 64, (NN + 63) / 64);
      gemm_bias<HIDC><<<g, 256, 0, stream>>>(h, Wcat, bcat, qkvs, NN, NCOLS);
    }

    edge_logits_csr<<<(EE + 3) / 4, 256, 0, stream>>>(qkvs, ei, csr, logc, csrc);

    float* dst = (l == NL - 1) ? out : h;
    node_aggr_ln<<<(NN + 3) / 4, 256, 0, stream>>>(
        qkvs, h, rowstart, csrc, logc,
        lng + (size_t)l * 128, lnb + (size_t)l * 128, dst);
  }
  (void)in_sizes; (void)n_in; (void)out_size; (void)ws_size;
}

// Round 3
// 750.310 us; speedup vs baseline: 6.0903x; 1.4955x over previous
//
#include <hip/hip_runtime.h>
#include <hip/hip_bf16.h>
#include <math.h>

#define NN 20000
#define EE 320000
#define DIN 64
#define HIDC 128
#define NCOLS 1664   // 512 q | 512 k | 512 v | 128 skip
#define QKVW 1536
#define NL 3

typedef __attribute__((ext_vector_type(8))) short bf16x8;
typedef __attribute__((ext_vector_type(8))) unsigned short u16x8;
typedef __attribute__((ext_vector_type(4))) float f32x4;

__device__ __forceinline__ float bf2f(unsigned short u) {
  union { unsigned i; float f; } v; v.i = ((unsigned)u) << 16; return v.f;
}
__device__ __forceinline__ unsigned short f2bf(float f) {
  __hip_bfloat16 b = __float2bfloat16(f);
  return *(unsigned short*)&b;
}

// ---------------- weight/bias prep ----------------
__global__ void build_wcatT(const float* __restrict__ Wq, const float* __restrict__ Wk,
                            const float* __restrict__ Wv, const float* __restrict__ Wsk,
                            unsigned short* __restrict__ wT) {
  int idx = blockIdx.x * 256 + threadIdx.x;
  if (idx >= NCOLS * HIDC) return;
  int n = idx >> 7, k = idx & 127;
  float v;
  if (n < 512)       v = Wq[(size_t)k * 512 + n];
  else if (n < 1024) v = Wk[(size_t)k * 512 + (n - 512)];
  else if (n < 1536) v = Wv[(size_t)k * 512 + (n - 1024)];
  else               v = Wsk[(size_t)k * 128 + (n - 1536)];
  wT[idx] = f2bf(v);
}

__global__ void build_bcat(const float* __restrict__ bq, const float* __restrict__ bk,
                           const float* __restrict__ bv, const float* __restrict__ bsk,
                           float* __restrict__ bcat) {
  int m = blockIdx.x * 256 + threadIdx.x;
  if (m >= NCOLS) return;
  float v;
  if (m < 512)       v = bq[m];
  else if (m < 1024) v = bk[m - 512];
  else if (m < 1536) v = bv[m - 1024];
  else               v = bsk[m - 1536];
  bcat[m] = v;
}

__global__ void conv_h(const float* __restrict__ h, unsigned short* __restrict__ hb) {
  int i = blockIdx.x * 256 + threadIdx.x;
  if (i >= NN * HIDC) return;
  hb[i] = f2bf(h[i]);
}

// ---------------- CSR build ----------------
__global__ void deg_hist(const int* __restrict__ ei, int* __restrict__ deg) {
  int e = blockIdx.x * 256 + threadIdx.x;
  if (e >= EE) return;
  atomicAdd(&deg[ei[EE + e]], 1);
}

__global__ __launch_bounds__(1024) void scan_deg(const int* __restrict__ deg,
                                                 int* __restrict__ rowstart) {
  __shared__ int part[1024];
  int t = threadIdx.x;
  int base = t * 20;
  int local[20];
  int s = 0;
#pragma unroll
  for (int i = 0; i < 20; i++) {
    int idx = base + i;
    int d = (idx < NN) ? deg[idx] : 0;
    local[i] = d;
    s += d;
  }
  part[t] = s;
  __syncthreads();
  for (int d = 1; d < 1024; d <<= 1) {
    int v = (t >= d) ? part[t - d] : 0;
    __syncthreads();
    part[t] += v;
    __syncthreads();
  }
  int run = part[t] - s;
#pragma unroll
  for (int i = 0; i < 20; i++) {
    int idx = base + i;
    if (idx < NN) rowstart[idx] = run;
    run += local[i];
  }
  if (t == 1023) rowstart[NN] = part[1023];
}

__global__ void csr_scatter(const int* __restrict__ ei, const int* __restrict__ rowstart,
                            int* __restrict__ cur, int* __restrict__ csr) {
  int e = blockIdx.x * 256 + threadIdx.x;
  if (e >= EE) return;
  int dst = ei[EE + e];
  int pos = atomicAdd(&cur[dst], 1);
  csr[rowstart[dst] + pos] = e;
}

// ---------------- fp32 tiled GEMM (input projection only, K=64) ----------------
template <int K>
__global__ __launch_bounds__(256) void gemm_bias(
    const float* __restrict__ A, const float* __restrict__ W,
    const float* __restrict__ bias, float* __restrict__ C,
    int n_rows, int n_cols) {
  constexpr int AS = K + 4;
  __shared__ __align__(16) float As[64][AS];
  __shared__ __align__(16) float Ws[K][64];
  const int tid = threadIdx.x;
  const int row0 = blockIdx.y * 64;
  const int col0 = blockIdx.x * 64;
  constexpr int K4 = K / 4;
#pragma unroll
  for (int p = 0; p < (64 * K4) / 256; ++p) {
    int it = p * 256 + tid;
    int r = it / K4, c4 = it - r * K4;
    float4 v = make_float4(0.f, 0.f, 0.f, 0.f);
    if (row0 + r < n_rows) v = *(const float4*)(A + (size_t)(row0 + r) * K + c4 * 4);
    *(float4*)&As[r][c4 * 4] = v;
  }
#pragma unroll
  for (int p = 0; p < (K * 16) / 256; ++p) {
    int it = p * 256 + tid;
    int k = it / 16, c4 = it - k * 16;
    *(float4*)&Ws[k][c4 * 4] = *(const float4*)(W + (size_t)k * n_cols + col0 + c4 * 4);
  }
  __syncthreads();
  const int tx = tid & 15, ty = tid >> 4;
  float acc[4][4];
#pragma unroll
  for (int i = 0; i < 4; i++)
#pragma unroll
    for (int j = 0; j < 4; j++) acc[i][j] = 0.f;

  for (int k = 0; k < K; k += 4) {
    float4 a[4], w[4];
#pragma unroll
    for (int i = 0; i < 4; i++) a[i] = *(const float4*)&As[ty * 4 + i][k];
#pragma unroll
    for (int kk = 0; kk < 4; kk++) w[kk] = *(const float4*)&Ws[k + kk][tx * 4];
#pragma unroll
    for (int i = 0; i < 4; i++) {
      const float av[4] = {a[i].x, a[i].y, a[i].z, a[i].w};
#pragma unroll
      for (int kk = 0; kk < 4; kk++) {
        acc[i][0] += av[kk] * w[kk].x;
        acc[i][1] += av[kk] * w[kk].y;
        acc[i][2] += av[kk] * w[kk].z;
        acc[i][3] += av[kk] * w[kk].w;
      }
    }
  }
#pragma unroll
  for (int i = 0; i < 4; i++) {
    int r = row0 + ty * 4 + i;
    if (r < n_rows) {
      int c = col0 + tx * 4;
      float4 b4 = *(const float4*)(bias + c);
      float4 o = make_float4(acc[i][0] + b4.x, acc[i][1] + b4.y,
                             acc[i][2] + b4.z, acc[i][3] + b4.w);
      *(float4*)(C + (size_t)r * n_cols + c) = o;
    }
  }
}

// ---------------- bf16 MFMA GEMM: qkv (bf16) + skip (fp32) ----------------
// block = 4 waves; wave w owns rows [by*64 + w*16, +16), cols [bx*64, +64)
// A = hb [NN][128] bf16, B = wT [1664][128] bf16 (pre-transposed)
__global__ __launch_bounds__(256) void mfma_gemm(
    const unsigned short* __restrict__ hb, const unsigned short* __restrict__ wT,
    const float* __restrict__ bias, unsigned short* __restrict__ qkvb,
    float* __restrict__ skipb) {
  const int wave = threadIdx.x >> 6, lane = threadIdx.x & 63;
  const int row0 = blockIdx.y * 64 + wave * 16;
  const int col0 = blockIdx.x * 64;
  const int lm = lane & 15, lk = lane >> 4;  // lk in 0..3

  int arow = row0 + lm;
  if (arow >= NN) arow = NN - 1;
  const unsigned short* ap = hb + (size_t)arow * HIDC + lk * 8;
  bf16x8 afrag[4];
#pragma unroll
  for (int kk = 0; kk < 4; kk++) afrag[kk] = *(const bf16x8*)(ap + kk * 32);

#pragma unroll
  for (int nf = 0; nf < 4; nf++) {
    const int col = col0 + nf * 16 + lm;
    const unsigned short* bp = wT + (size_t)col * HIDC + lk * 8;
    f32x4 acc = {0.f, 0.f, 0.f, 0.f};
#pragma unroll
    for (int kk = 0; kk < 4; kk++) {
      bf16x8 bfrag = *(const bf16x8*)(bp + kk * 32);
      acc = __builtin_amdgcn_mfma_f32_16x16x32_bf16(afrag[kk], bfrag, acc, 0, 0, 0);
    }
    const float bv = bias[col];
    // C/D layout: col = lane&15, row = (lane>>4)*4 + i  [m89/m91 verified]
    if (col0 < QKVW) {
#pragma unroll
      for (int i = 0; i < 4; i++) {
        int r = row0 + lk * 4 + i;
        if (r < NN) qkvb[(size_t)r * QKVW + col] = f2bf(acc[i] + bv);
      }
    } else {
#pragma unroll
      for (int i = 0; i < 4; i++) {
        int r = row0 + lk * 4 + i;
        if (r < NN) skipb[(size_t)r * HIDC + (col - QKVW)] = acc[i] + bv;
      }
    }
  }
}

// ---------------- edge logits (CSR-ordered, bf16 gathers) ----------------
__global__ __launch_bounds__(256) void edge_logits_csr(
    const unsigned short* __restrict__ qkvb, const int* __restrict__ ei,
    const int* __restrict__ csr, float* __restrict__ logc,
    int* __restrict__ csrc) {
  int j = blockIdx.x * 4 + (threadIdx.x >> 6);
  if (j >= EE) return;
  int lane = threadIdx.x & 63;
  int hh = lane >> 4, t = lane & 15;
  int e = csr[j];
  int src = ei[e], dst = ei[EE + e];
  u16x8 q8 = *(const u16x8*)(qkvb + (size_t)dst * QKVW + hh * 128 + t * 8);
  u16x8 k8 = *(const u16x8*)(qkvb + (size_t)src * QKVW + 512 + hh * 128 + t * 8);
  float p = 0.f;
#pragma unroll
  for (int i = 0; i < 8; i++) p += bf2f(q8[i]) * bf2f(k8[i]);
  p += __shfl_xor(p, 1);
  p += __shfl_xor(p, 2);
  p += __shfl_xor(p, 4);
  p += __shfl_xor(p, 8);
  if (t == 0) logc[j * 4 + hh] = p * 0.08838834764831845f;  // 1/sqrt(128)
  if (lane == 0) csrc[j] = src;
}

// ---------------- node aggregation + skip + residual + LN ----------------
// one wave per node; lane covers dims {2*lane, 2*lane+1}
__global__ __launch_bounds__(256) void node_aggr_ln(
    const unsigned short* __restrict__ qkvb, const float* __restrict__ skipb,
    const float* __restrict__ h,
    const int* __restrict__ rowstart, const int* __restrict__ csrc,
    const float* __restrict__ logc, const float* __restrict__ gamma,
    const float* __restrict__ beta, float* __restrict__ outp,
    unsigned short* __restrict__ hb_out) {
  int n = blockIdx.x * 4 + (threadIdx.x >> 6);
  if (n >= NN) return;
  int lane = threadIdx.x & 63;
  int j0 = rowstart[n], j1 = rowstart[n + 1];

  // pass A: online softmax stats, lanes parallel over edges
  float m0 = -INFINITY, m1 = -INFINITY, m2 = -INFINITY, m3 = -INFINITY;
  float s0 = 0.f, s1 = 0.f, s2 = 0.f, s3 = 0.f;
  for (int j = j0 + lane; j < j1; j += 64) {
    float4 lg = *(const float4*)(logc + (size_t)j * 4);
    float nm;
    nm = fmaxf(m0, lg.x); s0 = s0 * expf(m0 - nm) + expf(lg.x - nm); m0 = nm;
    nm = fmaxf(m1, lg.y); s1 = s1 * expf(m1 - nm) + expf(lg.y - nm); m1 = nm;
    nm = fmaxf(m2, lg.z); s2 = s2 * expf(m2 - nm) + expf(lg.z - nm); m2 = nm;
    nm = fmaxf(m3, lg.w); s3 = s3 * expf(m3 - nm) + expf(lg.w - nm); m3 = nm;
  }
  float M0 = m0, M1 = m1, M2 = m2, M3 = m3;
#pragma unroll
  for (int d = 1; d < 64; d <<= 1) {
    M0 = fmaxf(M0, __shfl_xor(M0, d));
    M1 = fmaxf(M1, __shfl_xor(M1, d));
    M2 = fmaxf(M2, __shfl_xor(M2, d));
    M3 = fmaxf(M3, __shfl_xor(M3, d));
  }
  float S0 = (s0 > 0.f) ? s0 * expf(m0 - M0) : 0.f;
  float S1 = (s1 > 0.f) ? s1 * expf(m1 - M1) : 0.f;
  float S2 = (s2 > 0.f) ? s2 * expf(m2 - M2) : 0.f;
  float S3 = (s3 > 0.f) ? s3 * expf(m3 - M3) : 0.f;
#pragma unroll
  for (int d = 1; d < 64; d <<= 1) {
    S0 += __shfl_xor(S0, d);
    S1 += __shfl_xor(S1, d);
    S2 += __shfl_xor(S2, d);
    S3 += __shfl_xor(S3, d);
  }
  float r0 = 0.25f / (S0 + 1e-16f);
  float r1 = 0.25f / (S1 + 1e-16f);
  float r2 = 0.25f / (S2 + 1e-16f);
  float r3 = 0.25f / (S3 + 1e-16f);

  // pass B: weighted V gather-accumulate
  float acc0 = 0.f, acc1 = 0.f;
  for (int j = j0; j < j1; ++j) {
    int src = csrc[j];
    float4 lg = *(const float4*)(logc + (size_t)j * 4);
    float w0 = expf(lg.x - M0) * r0;
    float w1 = expf(lg.y - M1) * r1;
    float w2 = expf(lg.z - M2) * r2;
    float w3 = expf(lg.w - M3) * r3;
    const unsigned short* vb = qkvb + (size_t)src * QKVW + 1024 + 2 * lane;
    ushort2 v0 = *(const ushort2*)(vb);
    ushort2 v1 = *(const ushort2*)(vb + 128);
    ushort2 v2 = *(const ushort2*)(vb + 256);
    ushort2 v3 = *(const ushort2*)(vb + 384);
    acc0 += w0 * bf2f(v0.x) + w1 * bf2f(v1.x) + w2 * bf2f(v2.x) + w3 * bf2f(v3.x);
    acc1 += w0 * bf2f(v0.y) + w1 * bf2f(v1.y) + w2 * bf2f(v2.y) + w3 * bf2f(v3.y);
  }

  // finalize: h + aggr + skip, LayerNorm, dual write (fp32 + bf16)
  int d0 = 2 * lane;
  size_t hbase = (size_t)n * HIDC;
  float2 hv = *(const float2*)(h + hbase + d0);
  float2 sk = *(const float2*)(skipb + hbase + d0);
  float u0 = hv.x + acc0 + sk.x;
  float u1 = hv.y + acc1 + sk.y;
  float ssum = u0 + u1;
#pragma unroll
  for (int d = 1; d < 64; d <<= 1) ssum += __shfl_xor(ssum, d);
  float mu = ssum * (1.f / 128.f);
  float dd0 = u0 - mu, dd1 = u1 - mu;
  float vs = dd0 * dd0 + dd1 * dd1;
#pragma unroll
  for (int d = 1; d < 64; d <<= 1) vs += __shfl_xor(vs, d);
  float inv = rsqrtf(vs * (1.f / 128.f) + 1e-5f);
  float2 g2 = *(const float2*)(gamma + d0);
  float2 b2 = *(const float2*)(beta + d0);
  float o0 = dd0 * inv * g2.x + b2.x;
  float o1 = dd1 * inv * g2.y + b2.y;
  *(float2*)(outp + hbase + d0) = make_float2(o0, o1);
  *(ushort2*)(hb_out + hbase + d0) = make_ushort2(f2bf(o0), f2bf(o1));
}

// ---------------- workspace layout (float offsets) ----------------
#define OFF_H      ((size_t)0)            // N*128
#define OFF_SKIP   ((size_t)2560000)      // N*128
#define OFF_LOGC   ((size_t)5120000)      // E*4
#define OFF_QKVB   ((size_t)6400000)      // N*1536 bf16 -> 15,360,000 floats
#define OFF_HB     ((size_t)21760000)     // N*128 bf16 -> 1,280,000 floats
#define OFF_WT     ((size_t)23040000)     // 1664*128 bf16 -> 106,496 floats
#define OFF_BCAT   ((size_t)23146496)     // 1664
#define OFF_CSR    ((size_t)23148160)     // E ints
#define OFF_SRC    ((size_t)23468160)     // E ints
#define OFF_ROW    ((size_t)23788160)     // N+1 ints
#define OFF_DEG    ((size_t)23808162)     // N ints
#define OFF_CUR    ((size_t)23828162)     // N ints
// total ~23.85M floats ≈ 95.4 MB

extern "C" void kernel_launch(void* const* d_in, const int* in_sizes, int n_in,
                              void* d_out, int out_size, void* d_ws, size_t ws_size,
                              hipStream_t stream) {
  const float* x    = (const float*)d_in[0];
  const int*   ei   = (const int*)d_in[1];
  const float* Win  = (const float*)d_in[2];
  const float* bin_ = (const float*)d_in[3];
  const float* Wq   = (const float*)d_in[4];
  const float* bq   = (const float*)d_in[5];
  const float* Wk   = (const float*)d_in[6];
  const float* bk   = (const float*)d_in[7];
  const float* Wv   = (const float*)d_in[8];
  const float* bv   = (const float*)d_in[9];
  const float* Wsk  = (const float*)d_in[10];
  const float* bsk  = (const float*)d_in[11];
  const float* lng  = (const float*)d_in[12];
  const float* lnb  = (const float*)d_in[13];
  float* out = (float*)d_out;
  float* ws = (float*)d_ws;

  float* h     = ws + OFF_H;
  float* skipb = ws + OFF_SKIP;
  float* logc  = ws + OFF_LOGC;
  unsigned short* qkvb = (unsigned short*)(ws + OFF_QKVB);
  unsigned short* hb   = (unsigned short*)(ws + OFF_HB);
  unsigned short* wT   = (unsigned short*)(ws + OFF_WT);
  float* bcat  = ws + OFF_BCAT;
  int* csr      = (int*)(ws + OFF_CSR);
  int* csrc     = (int*)(ws + OFF_SRC);
  int* rowstart = (int*)(ws + OFF_ROW);
  int* deg      = (int*)(ws + OFF_DEG);
  int* cur      = (int*)(ws + OFF_CUR);

  // ---- CSR build ----
  hipMemsetAsync(deg, 0, NN * sizeof(int), stream);
  hipMemsetAsync(cur, 0, NN * sizeof(int), stream);
  deg_hist<<<(EE + 255) / 256, 256, 0, stream>>>(ei, deg);
  scan_deg<<<1, 1024, 0, stream>>>(deg, rowstart);
  csr_scatter<<<(EE + 255) / 256, 256, 0, stream>>>(ei, rowstart, cur, csr);

  // ---- input projection (fp32) + bf16 copy ----
  {
    dim3 g(HIDC / 64, (NN + 63) / 64);
    gemm_bias<DIN><<<g, 256, 0, stream>>>(x, Win, bin_, h, NN, HIDC);
  }
  conv_h<<<(NN * HIDC + 255) / 256, 256, 0, stream>>>(h, hb);

  for (int l = 0; l < NL; ++l) {
    build_wcatT<<<(NCOLS * HIDC + 255) / 256, 256, 0, stream>>>(
        Wq + (size_t)l * HIDC * 512, Wk + (size_t)l * HIDC * 512,
        Wv + (size_t)l * HIDC * 512, Wsk + (size_t)l * HIDC * HIDC, wT);
    build_bcat<<<(NCOLS + 255) / 256, 256, 0, stream>>>(
        bq + (size_t)l * 512, bk + (size_t)l * 512, bv + (size_t)l * 512,
        bsk + (size_t)l * 128, bcat);

    {
      dim3 g(NCOLS / 64, (NN + 63) / 64);
      mfma_gemm<<<g, 256, 0, stream>>>(hb, wT, bcat, qkvb, skipb);
    }

    edge_logits_csr<<<(EE + 3) / 4, 256, 0, stream>>>(qkvb, ei, csr, logc, csrc);

    float* dst = (l == NL - 1) ? out : h;
    node_aggr_ln<<<(NN + 3) / 4, 256, 0, stream>>>(
        qkvb, skipb, h, rowstart, csrc, logc,
        lng + (size_t)l * 128, lnb + (size_t)l * 128, dst, hb);
  }
  (void)in_sizes; (void)n_in; (void)out_size; (void)ws_size;
}

// Round 4
// 469.834 us; speedup vs baseline: 9.7260x; 1.5970x over previous
//
#include <hip/hip_runtime.h>
#include <hip/hip_bf16.h>
#include <math.h>

#define NN 20000
#define EE 320000
#define DIN 64
#define HIDC 128
#define NCOLS 1664   // 512 q | 512 k | 512 v | 128 skip
#define QKVW 1536
#define NL 3

typedef __attribute__((ext_vector_type(8))) short bf16x8;
typedef __attribute__((ext_vector_type(8))) unsigned short u16x8;
typedef __attribute__((ext_vector_type(4))) float f32x4;

__device__ __forceinline__ float bf2f(unsigned short u) {
  union { unsigned i; float f; } v; v.i = ((unsigned)u) << 16; return v.f;
}
__device__ __forceinline__ unsigned short f2bf(float f) {
  __hip_bfloat16 b = __float2bfloat16(f);
  return *(unsigned short*)&b;
}

// ---------------- weight/bias/input prep ----------------
__global__ void build_wcatT(const float* __restrict__ Wq, const float* __restrict__ Wk,
                            const float* __restrict__ Wv, const float* __restrict__ Wsk,
                            unsigned short* __restrict__ wT) {
  int idx = blockIdx.x * 256 + threadIdx.x;
  if (idx >= NCOLS * HIDC) return;
  int n = idx >> 7, k = idx & 127;
  float v;
  if (n < 512)       v = Wq[(size_t)k * 512 + n];
  else if (n < 1024) v = Wk[(size_t)k * 512 + (n - 512)];
  else if (n < 1536) v = Wv[(size_t)k * 512 + (n - 1024)];
  else               v = Wsk[(size_t)k * 128 + (n - 1536)];
  wT[idx] = f2bf(v);
}

__global__ void build_winT(const float* __restrict__ Win, unsigned short* __restrict__ winT) {
  int idx = blockIdx.x * 256 + threadIdx.x;
  if (idx >= HIDC * DIN) return;
  int c = idx >> 6, k = idx & 63;
  winT[idx] = f2bf(Win[(size_t)k * HIDC + c]);
}

__global__ void build_bcat(const float* __restrict__ bq, const float* __restrict__ bk,
                           const float* __restrict__ bv, const float* __restrict__ bsk,
                           float* __restrict__ bcat) {
  int m = blockIdx.x * 256 + threadIdx.x;
  if (m >= NCOLS) return;
  float v;
  if (m < 512)       v = bq[m];
  else if (m < 1024) v = bk[m - 512];
  else if (m < 1536) v = bv[m - 1024];
  else               v = bsk[m - 1536];
  bcat[m] = v;
}

__global__ void conv_x(const float* __restrict__ x, unsigned short* __restrict__ xb) {
  int i = blockIdx.x * 256 + threadIdx.x;
  if (i * 4 >= NN * DIN) return;
  float4 v = *(const float4*)(x + (size_t)i * 4);
  ushort4 o = make_ushort4(f2bf(v.x), f2bf(v.y), f2bf(v.z), f2bf(v.w));
  *(ushort4*)(xb + (size_t)i * 4) = o;
}

// ---------------- CSR build ----------------
__global__ void deg_hist(const int* __restrict__ ei, int* __restrict__ deg) {
  int e = blockIdx.x * 256 + threadIdx.x;
  if (e >= EE) return;
  atomicAdd(&deg[ei[EE + e]], 1);
}

__global__ __launch_bounds__(1024) void scan_deg(const int* __restrict__ deg,
                                                 int* __restrict__ rowstart) {
  __shared__ int part[1024];
  int t = threadIdx.x;
  int base = t * 20;
  int local[20];
  int s = 0;
#pragma unroll
  for (int i = 0; i < 20; i++) {
    int idx = base + i;
    int d = (idx < NN) ? deg[idx] : 0;
    local[i] = d;
    s += d;
  }
  part[t] = s;
  __syncthreads();
  for (int d = 1; d < 1024; d <<= 1) {
    int v = (t >= d) ? part[t - d] : 0;
    __syncthreads();
    part[t] += v;
    __syncthreads();
  }
  int run = part[t] - s;
#pragma unroll
  for (int i = 0; i < 20; i++) {
    int idx = base + i;
    if (idx < NN) rowstart[idx] = run;
    run += local[i];
  }
  if (t == 1023) rowstart[NN] = part[1023];
}

__global__ void csr_scatter(const int* __restrict__ ei, const int* __restrict__ rowstart,
                            int* __restrict__ cur, int* __restrict__ csrc) {
  int e = blockIdx.x * 256 + threadIdx.x;
  if (e >= EE) return;
  int src = ei[e], dst = ei[EE + e];
  int pos = atomicAdd(&cur[dst], 1);
  csrc[rowstart[dst] + pos] = src;
}

// ---------------- tiled MFMA GEMM (BM=BN=128) ----------------
// LDS tiles swizzled: phys 16B-chunk c holds logical chunk c ^ (row&7)
__device__ __forceinline__ void gl_lds16(const void* g, void* l) {
  __builtin_amdgcn_global_load_lds((const unsigned int*)g, (unsigned int*)l, 16, 0, 0);
}

template <int K>
__device__ __forceinline__ void stage_tile(const unsigned short* gbase,
                                           unsigned char* lbase, int tid) {
  constexpr int CH = K / 8;            // 16B chunks per row
  constexpr int ISS = (128 * CH) / 256;
  int wave = tid >> 6;
#pragma unroll
  for (int p = 0; p < ISS; p++) {
    int slot = p * 256 + tid;
    int row = slot / CH, ch = slot % CH;
    const unsigned short* src = gbase + (size_t)row * K + ((ch ^ (row & 7)) * 8);
    unsigned char* ldst = lbase + (size_t)(p * 256 + wave * 64) * 16;
    gl_lds16(src, ldst);
  }
}

template <int K>
__device__ __forceinline__ bf16x8 read_frag(const unsigned char* lbase, int row, int kk, int lk) {
  int ch = (kk * 4 + lk) ^ (row & 7);
  return *(const bf16x8*)(lbase + (size_t)row * (K * 2) + ch * 16);
}

// MODE 0: A=hb[NN][128], BT=wT[1664][128]; bf16 out to qkvb (cols<1536), fp32 skip tile
// MODE 1: A=xb[NN][64],  BT=winT[128][64]; fp32 out to h AND bf16 out to hb
template <int K, int MODE>
__global__ __launch_bounds__(256) void mfma_gemm_t(
    const unsigned short* __restrict__ A, const unsigned short* __restrict__ BT,
    const float* __restrict__ bias, unsigned short* __restrict__ outb,
    float* __restrict__ outf) {
  constexpr int LDSZ = (512 * K > 34816) ? 512 * K : 34816;
  __shared__ __align__(16) unsigned char LDS[LDSZ];
  const int tid = threadIdx.x;
  const int lane = tid & 63;
  const int wave = tid >> 6;
  const int lm = lane & 15, lk = lane >> 4;
  const int wm = wave >> 1, wn = wave & 1;
  const int row0 = blockIdx.y * 128, col0 = blockIdx.x * 128;
  unsigned char* aL = LDS;
  unsigned char* bL = LDS + 128 * K * 2;

  stage_tile<K>(A + (size_t)row0 * K, aL, tid);
  stage_tile<K>(BT + (size_t)col0 * K, bL, tid);
  __syncthreads();

  constexpr int KK = K / 32;
  f32x4 acc[4][4] = {};
  bf16x8 af[4][KK];
#pragma unroll
  for (int mf = 0; mf < 4; mf++)
#pragma unroll
    for (int kk = 0; kk < KK; kk++)
      af[mf][kk] = read_frag<K>(aL, wm * 64 + mf * 16 + lm, kk, lk);

#pragma unroll
  for (int nf = 0; nf < 4; nf++) {
    bf16x8 bf[KK];
#pragma unroll
    for (int kk = 0; kk < KK; kk++)
      bf[kk] = read_frag<K>(bL, wn * 64 + nf * 16 + lm, kk, lk);
#pragma unroll
    for (int mf = 0; mf < 4; mf++)
#pragma unroll
      for (int kk = 0; kk < KK; kk++)
        acc[mf][nf] = __builtin_amdgcn_mfma_f32_16x16x32_bf16(af[mf][kk], bf[kk],
                                                              acc[mf][nf], 0, 0, 0);
  }
  __syncthreads();  // all LDS reads done before bounce reuse

  if (MODE == 0 && blockIdx.x == NCOLS / 128 - 1) {
    // skip tile: fp32 direct to skipb [NN][128]
#pragma unroll
    for (int nf = 0; nf < 4; nf++) {
      int c = wn * 64 + nf * 16 + lm;
      float bv = bias[col0 + c];
#pragma unroll
      for (int mf = 0; mf < 4; mf++)
#pragma unroll
        for (int i = 0; i < 4; i++) {
          int r = row0 + wm * 64 + mf * 16 + lk * 4 + i;
          if (r < NN) outf[(size_t)r * HIDC + c] = acc[mf][nf][i] + bv;
        }
    }
  } else {
    // bf16 bounce: LDS [128][136] bf16
    unsigned short* bb = (unsigned short*)LDS;
#pragma unroll
    for (int nf = 0; nf < 4; nf++) {
      int c = wn * 64 + nf * 16 + lm;
      float bv = bias[col0 + c];
#pragma unroll
      for (int mf = 0; mf < 4; mf++)
#pragma unroll
        for (int i = 0; i < 4; i++) {
          int row = wm * 64 + mf * 16 + lk * 4 + i;
          bb[row * 136 + c] = f2bf(acc[mf][nf][i] + bv);
          if (MODE == 1) {
            int r = row0 + row;
            if (r < NN) outf[(size_t)r * HIDC + c] = acc[mf][nf][i] + bv;
          }
        }
    }
    __syncthreads();
    constexpr int STRIDE = (MODE == 0) ? QKVW : HIDC;
#pragma unroll
    for (int p = 0; p < 8; p++) {
      int idx = p * 256 + tid;
      int row = idx >> 4, c = idx & 15;
      int gr = row0 + row;
      if (gr < NN) {
        uint4 v = *(const uint4*)(bb + row * 136 + c * 8);
        *(uint4*)(outb + (size_t)gr * STRIDE + col0 + c * 8) = v;
      }
    }
  }
}

// ---------------- fused edge+node kernel ----------------
// one wave per node; lane = hh*16 + t (head hh, dim-chunk t -> dims t*8..t*8+7)
__global__ __launch_bounds__(256) void node_fused(
    const unsigned short* __restrict__ qkvb, const float* __restrict__ skipb,
    const float* __restrict__ h, const int* __restrict__ rowstart,
    const int* __restrict__ csrc, float* __restrict__ logc,
    const float* __restrict__ gamma, const float* __restrict__ beta,
    float* __restrict__ outp, unsigned short* __restrict__ hb_out) {
  int n = blockIdx.x * 4 + (threadIdx.x >> 6);
  if (n >= NN) return;
  int lane = threadIdx.x & 63;
  int hh = lane >> 4, t = lane & 15;
  int j0 = rowstart[n], j1 = rowstart[n + 1];

  // q row in registers
  u16x8 q8 = *(const u16x8*)(qkvb + (size_t)n * QKVW + hh * 128 + t * 8);
  float qf[8];
#pragma unroll
  for (int i = 0; i < 8; i++) qf[i] = bf2f(q8[i]);

  // pass 0: logits (serial over edges, unroll 2)
  {
    int j = j0;
    for (; j + 1 < j1; j += 2) {
      int sA = csrc[j], sB = csrc[j + 1];
      u16x8 kA = *(const u16x8*)(qkvb + (size_t)sA * QKVW + 512 + hh * 128 + t * 8);
      u16x8 kB = *(const u16x8*)(qkvb + (size_t)sB * QKVW + 512 + hh * 128 + t * 8);
      float pA = 0.f, pB = 0.f;
#pragma unroll
      for (int i = 0; i < 8; i++) { pA += qf[i] * bf2f(kA[i]); pB += qf[i] * bf2f(kB[i]); }
      pA += __shfl_xor(pA, 1); pB += __shfl_xor(pB, 1);
      pA += __shfl_xor(pA, 2); pB += __shfl_xor(pB, 2);
      pA += __shfl_xor(pA, 4); pB += __shfl_xor(pB, 4);
      pA += __shfl_xor(pA, 8); pB += __shfl_xor(pB, 8);
      if (t == 0) {
        logc[(size_t)j * 4 + hh] = pA * 0.08838834764831845f;
        logc[(size_t)(j + 1) * 4 + hh] = pB * 0.08838834764831845f;
      }
    }
    if (j < j1) {
      int sA = csrc[j];
      u16x8 kA = *(const u16x8*)(qkvb + (size_t)sA * QKVW + 512 + hh * 128 + t * 8);
      float pA = 0.f;
#pragma unroll
      for (int i = 0; i < 8; i++) pA += qf[i] * bf2f(kA[i]);
      pA += __shfl_xor(pA, 1);
      pA += __shfl_xor(pA, 2);
      pA += __shfl_xor(pA, 4);
      pA += __shfl_xor(pA, 8);
      if (t == 0) logc[(size_t)j * 4 + hh] = pA * 0.08838834764831845f;
    }
  }
  __asm__ volatile("s_waitcnt vmcnt(0)" ::: "memory");

  // pass A: softmax stats (edge-parallel over lanes)
  float m0 = -INFINITY, m1 = -INFINITY, m2 = -INFINITY, m3 = -INFINITY;
  float s0 = 0.f, s1 = 0.f, s2 = 0.f, s3 = 0.f;
  for (int jj = j0 + lane; jj < j1; jj += 64) {
    float4 lg = *(const float4*)(logc + (size_t)jj * 4);
    float nm;
    nm = fmaxf(m0, lg.x); s0 = s0 * __expf(m0 - nm) + __expf(lg.x - nm); m0 = nm;
    nm = fmaxf(m1, lg.y); s1 = s1 * __expf(m1 - nm) + __expf(lg.y - nm); m1 = nm;
    nm = fmaxf(m2, lg.z); s2 = s2 * __expf(m2 - nm) + __expf(lg.z - nm); m2 = nm;
    nm = fmaxf(m3, lg.w); s3 = s3 * __expf(m3 - nm) + __expf(lg.w - nm); m3 = nm;
  }
  float M0 = m0, M1 = m1, M2 = m2, M3 = m3;
#pragma unroll
  for (int d = 1; d < 64; d <<= 1) {
    M0 = fmaxf(M0, __shfl_xor(M0, d));
    M1 = fmaxf(M1, __shfl_xor(M1, d));
    M2 = fmaxf(M2, __shfl_xor(M2, d));
    M3 = fmaxf(M3, __shfl_xor(M3, d));
  }
  float S0 = (s0 > 0.f) ? s0 * __expf(m0 - M0) : 0.f;
  float S1 = (s1 > 0.f) ? s1 * __expf(m1 - M1) : 0.f;
  float S2 = (s2 > 0.f) ? s2 * __expf(m2 - M2) : 0.f;
  float S3 = (s3 > 0.f) ? s3 * __expf(m3 - M3) : 0.f;
#pragma unroll
  for (int d = 1; d < 64; d <<= 1) {
    S0 += __shfl_xor(S0, d);
    S1 += __shfl_xor(S1, d);
    S2 += __shfl_xor(S2, d);
    S3 += __shfl_xor(S3, d);
  }
  float Msel = (hh & 2) ? ((hh & 1) ? M3 : M2) : ((hh & 1) ? M1 : M0);
  float Ssel = (hh & 2) ? ((hh & 1) ? S3 : S2) : ((hh & 1) ? S1 : S0);
  float Rsel = 0.25f / (Ssel + 1e-16f);

  // pass B: weighted V gather (serial, unroll 2); lane accumulates dims of head hh
  float acc8[8] = {0.f, 0.f, 0.f, 0.f, 0.f, 0.f, 0.f, 0.f};
  {
    int j = j0;
    for (; j + 1 < j1; j += 2) {
      int sA = csrc[j], sB = csrc[j + 1];
      u16x8 vA = *(const u16x8*)(qkvb + (size_t)sA * QKVW + 1024 + hh * 128 + t * 8);
      u16x8 vB = *(const u16x8*)(qkvb + (size_t)sB * QKVW + 1024 + hh * 128 + t * 8);
      float lgA = logc[(size_t)j * 4 + hh];
      float lgB = logc[(size_t)(j + 1) * 4 + hh];
      float wA = __expf(lgA - Msel) * Rsel;
      float wB = __expf(lgB - Msel) * Rsel;
#pragma unroll
      for (int i = 0; i < 8; i++) acc8[i] += wA * bf2f(vA[i]) + wB * bf2f(vB[i]);
    }
    if (j < j1) {
      int sA = csrc[j];
      u16x8 vA = *(const u16x8*)(qkvb + (size_t)sA * QKVW + 1024 + hh * 128 + t * 8);
      float lgA = logc[(size_t)j * 4 + hh];
      float wA = __expf(lgA - Msel) * Rsel;
#pragma unroll
      for (int i = 0; i < 8; i++) acc8[i] += wA * bf2f(vA[i]);
    }
  }
  // head-mean fold: sum over head groups
#pragma unroll
  for (int i = 0; i < 8; i++) {
    acc8[i] += __shfl_xor(acc8[i], 16);
    acc8[i] += __shfl_xor(acc8[i], 32);
  }

  // finalize: u = h + aggr + skip; LayerNorm over 128 dims (each 16-lane group has all dims)
  size_t hbase = (size_t)n * HIDC;
  float u[8];
  {
    float4 h0 = *(const float4*)(h + hbase + t * 8);
    float4 h1 = *(const float4*)(h + hbase + t * 8 + 4);
    float4 k0 = *(const float4*)(skipb + hbase + t * 8);
    float4 k1 = *(const float4*)(skipb + hbase + t * 8 + 4);
    u[0] = h0.x + acc8[0] + k0.x; u[1] = h0.y + acc8[1] + k0.y;
    u[2] = h0.z + acc8[2] + k0.z; u[3] = h0.w + acc8[3] + k0.w;
    u[4] = h1.x + acc8[4] + k1.x; u[5] = h1.y + acc8[5] + k1.y;
    u[6] = h1.z + acc8[6] + k1.z; u[7] = h1.w + acc8[7] + k1.w;
  }
  float su = 0.f;
#pragma unroll
  for (int i = 0; i < 8; i++) su += u[i];
#pragma unroll
  for (int d = 1; d < 16; d <<= 1) su += __shfl_xor(su, d);
  float mu = su * (1.f / 128.f);
  float vs = 0.f;
#pragma unroll
  for (int i = 0; i < 8; i++) { u[i] -= mu; vs += u[i] * u[i]; }
#pragma unroll
  for (int d = 1; d < 16; d <<= 1) vs += __shfl_xor(vs, d);
  float inv = rsqrtf(vs * (1.f / 128.f) + 1e-5f);
  if (hh == 0) {
    float4 g0 = *(const float4*)(gamma + t * 8);
    float4 g1 = *(const float4*)(gamma + t * 8 + 4);
    float4 b0 = *(const float4*)(beta + t * 8);
    float4 b1 = *(const float4*)(beta + t * 8 + 4);
    float o[8];
    o[0] = u[0] * inv * g0.x + b0.x; o[1] = u[1] * inv * g0.y + b0.y;
    o[2] = u[2] * inv * g0.z + b0.z; o[3] = u[3] * inv * g0.w + b0.w;
    o[4] = u[4] * inv * g1.x + b1.x; o[5] = u[5] * inv * g1.y + b1.y;
    o[6] = u[6] * inv * g1.z + b1.z; o[7] = u[7] * inv * g1.w + b1.w;
    *(float4*)(outp + hbase + t * 8)     = make_float4(o[0], o[1], o[2], o[3]);
    *(float4*)(outp + hbase + t * 8 + 4) = make_float4(o[4], o[5], o[6], o[7]);
    ushort4 c0 = make_ushort4(f2bf(o[0]), f2bf(o[1]), f2bf(o[2]), f2bf(o[3]));
    ushort4 c1 = make_ushort4(f2bf(o[4]), f2bf(o[5]), f2bf(o[6]), f2bf(o[7]));
    *(ushort4*)(hb_out + hbase + t * 8)     = c0;
    *(ushort4*)(hb_out + hbase + t * 8 + 4) = c1;
  }
}

// ---------------- workspace layout (float offsets, all 16B-aligned) ----------------
#define OFF_H      ((size_t)0)            // N*128
#define OFF_SKIP   ((size_t)2560000)      // N*128
#define OFF_LOGC   ((size_t)5120000)      // E*4
#define OFF_QKVB   ((size_t)6400000)      // N*1536 bf16
#define OFF_HB     ((size_t)21760000)     // N*128 bf16
#define OFF_XB     ((size_t)23040000)     // N*64 bf16
#define OFF_WT     ((size_t)23680000)     // 1664*128 bf16
#define OFF_WINT   ((size_t)23786496)     // 128*64 bf16
#define OFF_BCAT   ((size_t)23790592)     // 1664
#define OFF_CSRC   ((size_t)23792256)     // E ints
#define OFF_ROW    ((size_t)24112256)     // N+1 ints
#define OFF_DEG    ((size_t)24132260)     // N ints
#define OFF_CUR    ((size_t)24152260)     // N ints
// end 24,172,260 floats ~ 96.7 MB

extern "C" void kernel_launch(void* const* d_in, const int* in_sizes, int n_in,
                              void* d_out, int out_size, void* d_ws, size_t ws_size,
                              hipStream_t stream) {
  const float* x    = (const float*)d_in[0];
  const int*   ei   = (const int*)d_in[1];
  const float* Win  = (const float*)d_in[2];
  const float* bin_ = (const float*)d_in[3];
  const float* Wq   = (const float*)d_in[4];
  const float* bq   = (const float*)d_in[5];
  const float* Wk   = (const float*)d_in[6];
  const float* bk   = (const float*)d_in[7];
  const float* Wv   = (const float*)d_in[8];
  const float* bv   = (const float*)d_in[9];
  const float* Wsk  = (const float*)d_in[10];
  const float* bsk  = (const float*)d_in[11];
  const float* lng  = (const float*)d_in[12];
  const float* lnb  = (const float*)d_in[13];
  float* out = (float*)d_out;
  float* ws = (float*)d_ws;

  float* h     = ws + OFF_H;
  float* skipb = ws + OFF_SKIP;
  float* logc  = ws + OFF_LOGC;
  unsigned short* qkvb = (unsigned short*)(ws + OFF_QKVB);
  unsigned short* hb   = (unsigned short*)(ws + OFF_HB);
  unsigned short* xb   = (unsigned short*)(ws + OFF_XB);
  unsigned short* wT   = (unsigned short*)(ws + OFF_WT);
  unsigned short* winT = (unsigned short*)(ws + OFF_WINT);
  float* bcat  = ws + OFF_BCAT;
  int* csrc     = (int*)(ws + OFF_CSRC);
  int* rowstart = (int*)(ws + OFF_ROW);
  int* deg      = (int*)(ws + OFF_DEG);
  int* cur      = (int*)(ws + OFF_CUR);

  // ---- CSR build ----
  hipMemsetAsync(deg, 0, NN * sizeof(int), stream);
  hipMemsetAsync(cur, 0, NN * sizeof(int), stream);
  deg_hist<<<(EE + 255) / 256, 256, 0, stream>>>(ei, deg);
  scan_deg<<<1, 1024, 0, stream>>>(deg, rowstart);
  csr_scatter<<<(EE + 255) / 256, 256, 0, stream>>>(ei, rowstart, cur, csrc);

  // ---- input projection via MFMA (K=64): h fp32 + hb bf16 ----
  conv_x<<<(NN * DIN / 4 + 255) / 256, 256, 0, stream>>>(x, xb);
  build_winT<<<(HIDC * DIN + 255) / 256, 256, 0, stream>>>(Win, winT);
  {
    dim3 g(1, (NN + 127) / 128);
    mfma_gemm_t<64, 1><<<g, 256, 0, stream>>>(xb, winT, bin_, hb, h);
  }

  for (int l = 0; l < NL; ++l) {
    build_wcatT<<<(NCOLS * HIDC + 255) / 256, 256, 0, stream>>>(
        Wq + (size_t)l * HIDC * 512, Wk + (size_t)l * HIDC * 512,
        Wv + (size_t)l * HIDC * 512, Wsk + (size_t)l * HIDC * HIDC, wT);
    build_bcat<<<(NCOLS + 255) / 256, 256, 0, stream>>>(
        bq + (size_t)l * 512, bk + (size_t)l * 512, bv + (size_t)l * 512,
        bsk + (size_t)l * 128, bcat);

    {
      dim3 g(NCOLS / 128, (NN + 127) / 128);
      mfma_gemm_t<128, 0><<<g, 256, 0, stream>>>(hb, wT, bcat, qkvb, skipb);
    }

    float* dst = (l == NL - 1) ? out : h;
    node_fused<<<(NN + 3) / 4, 256, 0, stream>>>(
        qkvb, skipb, h, rowstart, csrc, logc,
        lng + (size_t)l * 128, lnb + (size_t)l * 128, dst, hb);
  }
  (void)in_sizes; (void)n_in; (void)out_size; (void)ws_size;
}

// Round 5
// 466.093 us; speedup vs baseline: 9.8041x; 1.0080x over previous
//
#include <hip/hip_runtime.h>
#include <hip/hip_bf16.h>
#include <math.h>

#define NN 20000
#define EE 320000
#define DIN 64
#define HIDC 128
#define NCOLS 1664   // 512 q | 512 k | 512 v | 128 skip
#define QKVW 1536
#define NL 3

typedef __attribute__((ext_vector_type(8))) short bf16x8;
typedef __attribute__((ext_vector_type(8))) unsigned short u16x8;
typedef __attribute__((ext_vector_type(4))) float f32x4;

__device__ __forceinline__ float bf2f(unsigned short u) {
  union { unsigned i; float f; } v; v.i = ((unsigned)u) << 16; return v.f;
}
__device__ __forceinline__ unsigned short f2bf(float f) {
  __hip_bfloat16 b = __float2bfloat16(f);
  return *(unsigned short*)&b;
}

// ---------------- weight/bias/input prep ----------------
__global__ void build_wcatT(const float* __restrict__ Wq, const float* __restrict__ Wk,
                            const float* __restrict__ Wv, const float* __restrict__ Wsk,
                            unsigned short* __restrict__ wT) {
  int idx = blockIdx.x * 256 + threadIdx.x;
  if (idx >= NCOLS * HIDC) return;
  int n = idx >> 7, k = idx & 127;
  float v;
  if (n < 512)       v = Wq[(size_t)k * 512 + n];
  else if (n < 1024) v = Wk[(size_t)k * 512 + (n - 512)];
  else if (n < 1536) v = Wv[(size_t)k * 512 + (n - 1024)];
  else               v = Wsk[(size_t)k * 128 + (n - 1536)];
  wT[idx] = f2bf(v);
}

__global__ void build_winT(const float* __restrict__ Win, unsigned short* __restrict__ winT) {
  int idx = blockIdx.x * 256 + threadIdx.x;
  if (idx >= HIDC * DIN) return;
  int c = idx >> 6, k = idx & 63;
  winT[idx] = f2bf(Win[(size_t)k * HIDC + c]);
}

__global__ void build_bcat(const float* __restrict__ bq, const float* __restrict__ bk,
                           const float* __restrict__ bv, const float* __restrict__ bsk,
                           float* __restrict__ bcat) {
  int m = blockIdx.x * 256 + threadIdx.x;
  if (m >= NCOLS) return;
  float v;
  if (m < 512)       v = bq[m];
  else if (m < 1024) v = bk[m - 512];
  else if (m < 1536) v = bv[m - 1024];
  else               v = bsk[m - 1536];
  bcat[m] = v;
}

__global__ void conv_x(const float* __restrict__ x, unsigned short* __restrict__ xb) {
  int i = blockIdx.x * 256 + threadIdx.x;
  if (i * 4 >= NN * DIN) return;
  float4 v = *(const float4*)(x + (size_t)i * 4);
  ushort4 o = make_ushort4(f2bf(v.x), f2bf(v.y), f2bf(v.z), f2bf(v.w));
  *(ushort4*)(xb + (size_t)i * 4) = o;
}

// ---------------- CSR build ----------------
__global__ void deg_hist(const int* __restrict__ ei, int* __restrict__ deg) {
  int e = blockIdx.x * 256 + threadIdx.x;
  if (e >= EE) return;
  atomicAdd(&deg[ei[EE + e]], 1);
}

__global__ __launch_bounds__(1024) void scan_deg(const int* __restrict__ deg,
                                                 int* __restrict__ rowstart) {
  __shared__ int part[1024];
  int t = threadIdx.x;
  int base = t * 20;
  int local[20];
  int s = 0;
#pragma unroll
  for (int i = 0; i < 20; i++) {
    int idx = base + i;
    int d = (idx < NN) ? deg[idx] : 0;
    local[i] = d;
    s += d;
  }
  part[t] = s;
  __syncthreads();
  for (int d = 1; d < 1024; d <<= 1) {
    int v = (t >= d) ? part[t - d] : 0;
    __syncthreads();
    part[t] += v;
    __syncthreads();
  }
  int run = part[t] - s;
#pragma unroll
  for (int i = 0; i < 20; i++) {
    int idx = base + i;
    if (idx < NN) rowstart[idx] = run;
    run += local[i];
  }
  if (t == 1023) rowstart[NN] = part[1023];
}

__global__ void csr_scatter(const int* __restrict__ ei, const int* __restrict__ rowstart,
                            int* __restrict__ cur, int* __restrict__ csrc) {
  int e = blockIdx.x * 256 + threadIdx.x;
  if (e >= EE) return;
  int src = ei[e], dst = ei[EE + e];
  int pos = atomicAdd(&cur[dst], 1);
  csrc[rowstart[dst] + pos] = src;
}

// ---------------- tiled MFMA GEMM (BM=BN=128) ----------------
__device__ __forceinline__ void gl_lds16(const void* g, void* l) {
  __builtin_amdgcn_global_load_lds((const unsigned int*)g, (unsigned int*)l, 16, 0, 0);
}

template <int K>
__device__ __forceinline__ void stage_tile(const unsigned short* gbase,
                                           unsigned char* lbase, int tid) {
  constexpr int CH = K / 8;
  constexpr int ISS = (128 * CH) / 256;
  int wave = tid >> 6;
#pragma unroll
  for (int p = 0; p < ISS; p++) {
    int slot = p * 256 + tid;
    int row = slot / CH, ch = slot % CH;
    const unsigned short* src = gbase + (size_t)row * K + ((ch ^ (row & 7)) * 8);
    unsigned char* ldst = lbase + (size_t)(p * 256 + wave * 64) * 16;
    gl_lds16(src, ldst);
  }
}

template <int K>
__device__ __forceinline__ bf16x8 read_frag(const unsigned char* lbase, int row, int kk, int lk) {
  int ch = (kk * 4 + lk) ^ (row & 7);
  return *(const bf16x8*)(lbase + (size_t)row * (K * 2) + ch * 16);
}

template <int K, int MODE>
__global__ __launch_bounds__(256) void mfma_gemm_t(
    const unsigned short* __restrict__ A, const unsigned short* __restrict__ BT,
    const float* __restrict__ bias, unsigned short* __restrict__ outb,
    float* __restrict__ outf) {
  constexpr int LDSZ = (512 * K > 34816) ? 512 * K : 34816;
  __shared__ __align__(16) unsigned char LDS[LDSZ];
  const int tid = threadIdx.x;
  const int lane = tid & 63;
  const int wave = tid >> 6;
  const int lm = lane & 15, lk = lane >> 4;
  const int wm = wave >> 1, wn = wave & 1;
  const int row0 = blockIdx.y * 128, col0 = blockIdx.x * 128;
  unsigned char* aL = LDS;
  unsigned char* bL = LDS + 128 * K * 2;

  stage_tile<K>(A + (size_t)row0 * K, aL, tid);
  stage_tile<K>(BT + (size_t)col0 * K, bL, tid);
  __syncthreads();

  constexpr int KK = K / 32;
  f32x4 acc[4][4] = {};
  bf16x8 af[4][KK];
#pragma unroll
  for (int mf = 0; mf < 4; mf++)
#pragma unroll
    for (int kk = 0; kk < KK; kk++)
      af[mf][kk] = read_frag<K>(aL, wm * 64 + mf * 16 + lm, kk, lk);

#pragma unroll
  for (int nf = 0; nf < 4; nf++) {
    bf16x8 bf[KK];
#pragma unroll
    for (int kk = 0; kk < KK; kk++)
      bf[kk] = read_frag<K>(bL, wn * 64 + nf * 16 + lm, kk, lk);
#pragma unroll
    for (int mf = 0; mf < 4; mf++)
#pragma unroll
      for (int kk = 0; kk < KK; kk++)
        acc[mf][nf] = __builtin_amdgcn_mfma_f32_16x16x32_bf16(af[mf][kk], bf[kk],
                                                              acc[mf][nf], 0, 0, 0);
  }
  __syncthreads();

  if (MODE == 0 && blockIdx.x == NCOLS / 128 - 1) {
#pragma unroll
    for (int nf = 0; nf < 4; nf++) {
      int c = wn * 64 + nf * 16 + lm;
      float bv = bias[col0 + c];
#pragma unroll
      for (int mf = 0; mf < 4; mf++)
#pragma unroll
        for (int i = 0; i < 4; i++) {
          int r = row0 + wm * 64 + mf * 16 + lk * 4 + i;
          if (r < NN) outf[(size_t)r * HIDC + c] = acc[mf][nf][i] + bv;
        }
    }
  } else {
    unsigned short* bb = (unsigned short*)LDS;
#pragma unroll
    for (int nf = 0; nf < 4; nf++) {
      int c = wn * 64 + nf * 16 + lm;
      float bv = bias[col0 + c];
#pragma unroll
      for (int mf = 0; mf < 4; mf++)
#pragma unroll
        for (int i = 0; i < 4; i++) {
          int row = wm * 64 + mf * 16 + lk * 4 + i;
          bb[row * 136 + c] = f2bf(acc[mf][nf][i] + bv);
          if (MODE == 1) {
            int r = row0 + row;
            if (r < NN) outf[(size_t)r * HIDC + c] = acc[mf][nf][i] + bv;
          }
        }
    }
    __syncthreads();
    constexpr int STRIDE = (MODE == 0) ? QKVW : HIDC;
#pragma unroll
    for (int p = 0; p < 8; p++) {
      int idx = p * 256 + tid;
      int row = idx >> 4, c = idx & 15;
      int gr = row0 + row;
      if (gr < NN) {
        uint4 v = *(const uint4*)(bb + row * 136 + c * 8);
        *(uint4*)(outb + (size_t)gr * STRIDE + col0 + c * 8) = v;
      }
    }
  }
}

// ---------------- fused single-pass flash-style node kernel ----------------
// one wave per node; lane = hh*16 + t (head hh, dims t*8..t*8+7)
__global__ __launch_bounds__(256) void node_fused(
    const unsigned short* __restrict__ qkvb, const float* __restrict__ skipb,
    const float* __restrict__ h, const int* __restrict__ rowstart,
    const int* __restrict__ csrc,
    const float* __restrict__ gamma, const float* __restrict__ beta,
    float* __restrict__ outp, unsigned short* __restrict__ hb_out) {
  int n = blockIdx.x * 4 + (threadIdx.x >> 6);
  if (n >= NN) return;
  int lane = threadIdx.x & 63;
  int hh = lane >> 4, t = lane & 15;
  int j0 = rowstart[n], j1 = rowstart[n + 1];

  // q fragment in registers
  u16x8 q8 = *(const u16x8*)(qkvb + (size_t)n * QKVW + hh * 128 + t * 8);
  float qf[8];
#pragma unroll
  for (int i = 0; i < 8; i++) qf[i] = bf2f(q8[i]);

  const unsigned short* kb = qkvb + 512 + hh * 128 + t * 8;
  const unsigned short* vb = qkvb + 1024 + hh * 128 + t * 8;

  float m = -INFINITY, s = 0.f;
  float acc[8] = {0.f, 0.f, 0.f, 0.f, 0.f, 0.f, 0.f, 0.f};

  int j = j0;
  for (; j + 1 < j1; j += 2) {
    int sA = csrc[j], sB = csrc[j + 1];
    u16x8 kA = *(const u16x8*)(kb + (size_t)sA * QKVW);
    u16x8 vA = *(const u16x8*)(vb + (size_t)sA * QKVW);
    u16x8 kB = *(const u16x8*)(kb + (size_t)sB * QKVW);
    u16x8 vB = *(const u16x8*)(vb + (size_t)sB * QKVW);
    float pA = 0.f, pB = 0.f;
#pragma unroll
    for (int i = 0; i < 8; i++) { pA += qf[i] * bf2f(kA[i]); pB += qf[i] * bf2f(kB[i]); }
    pA += __shfl_xor(pA, 1); pB += __shfl_xor(pB, 1);
    pA += __shfl_xor(pA, 2); pB += __shfl_xor(pB, 2);
    pA += __shfl_xor(pA, 4); pB += __shfl_xor(pB, 4);
    pA += __shfl_xor(pA, 8); pB += __shfl_xor(pB, 8);
    float lgA = pA * 0.08838834764831845f;
    float lgB = pB * 0.08838834764831845f;
    if (lgA > m) {
      float r = __expf(m - lgA);  // exp(-inf)=0 handles first edge
      s *= r;
#pragma unroll
      for (int i = 0; i < 8; i++) acc[i] *= r;
      m = lgA;
    }
    float wA = __expf(lgA - m);
    s += wA;
#pragma unroll
    for (int i = 0; i < 8; i++) acc[i] += wA * bf2f(vA[i]);
    if (lgB > m) {
      float r = __expf(m - lgB);
      s *= r;
#pragma unroll
      for (int i = 0; i < 8; i++) acc[i] *= r;
      m = lgB;
    }
    float wB = __expf(lgB - m);
    s += wB;
#pragma unroll
    for (int i = 0; i < 8; i++) acc[i] += wB * bf2f(vB[i]);
  }
  if (j < j1) {
    int sA = csrc[j];
    u16x8 kA = *(const u16x8*)(kb + (size_t)sA * QKVW);
    u16x8 vA = *(const u16x8*)(vb + (size_t)sA * QKVW);
    float pA = 0.f;
#pragma unroll
    for (int i = 0; i < 8; i++) pA += qf[i] * bf2f(kA[i]);
    pA += __shfl_xor(pA, 1);
    pA += __shfl_xor(pA, 2);
    pA += __shfl_xor(pA, 4);
    pA += __shfl_xor(pA, 8);
    float lgA = pA * 0.08838834764831845f;
    if (lgA > m) {
      float r = __expf(m - lgA);
      s *= r;
#pragma unroll
      for (int i = 0; i < 8; i++) acc[i] *= r;
      m = lgA;
    }
    float wA = __expf(lgA - m);
    s += wA;
#pragma unroll
    for (int i = 0; i < 8; i++) acc[i] += wA * bf2f(vA[i]);
  }

  // normalize + head-mean fold (0.25/s), sum across the 4 head groups
  float rsel = 0.25f / (s + 1e-16f);
#pragma unroll
  for (int i = 0; i < 8; i++) {
    float a = acc[i] * rsel;
    a += __shfl_xor(a, 16);
    a += __shfl_xor(a, 32);
    acc[i] = a;
  }

  // finalize: u = h + aggr + skip; LayerNorm over 128 dims
  size_t hbase = (size_t)n * HIDC;
  float u[8];
  {
    float4 h0 = *(const float4*)(h + hbase + t * 8);
    float4 h1 = *(const float4*)(h + hbase + t * 8 + 4);
    float4 k0 = *(const float4*)(skipb + hbase + t * 8);
    float4 k1 = *(const float4*)(skipb + hbase + t * 8 + 4);
    u[0] = h0.x + acc[0] + k0.x; u[1] = h0.y + acc[1] + k0.y;
    u[2] = h0.z + acc[2] + k0.z; u[3] = h0.w + acc[3] + k0.w;
    u[4] = h1.x + acc[4] + k1.x; u[5] = h1.y + acc[5] + k1.y;
    u[6] = h1.z + acc[6] + k1.z; u[7] = h1.w + acc[7] + k1.w;
  }
  float su = 0.f;
#pragma unroll
  for (int i = 0; i < 8; i++) su += u[i];
#pragma unroll
  for (int d = 1; d < 16; d <<= 1) su += __shfl_xor(su, d);
  float mu = su * (1.f / 128.f);
  float vs = 0.f;
#pragma unroll
  for (int i = 0; i < 8; i++) { u[i] -= mu; vs += u[i] * u[i]; }
#pragma unroll
  for (int d = 1; d < 16; d <<= 1) vs += __shfl_xor(vs, d);
  float inv = rsqrtf(vs * (1.f / 128.f) + 1e-5f);
  if (hh == 0) {
    float4 g0 = *(const float4*)(gamma + t * 8);
    float4 g1 = *(const float4*)(gamma + t * 8 + 4);
    float4 b0 = *(const float4*)(beta + t * 8);
    float4 b1 = *(const float4*)(beta + t * 8 + 4);
    float o[8];
    o[0] = u[0] * inv * g0.x + b0.x; o[1] = u[1] * inv * g0.y + b0.y;
    o[2] = u[2] * inv * g0.z + b0.z; o[3] = u[3] * inv * g0.w + b0.w;
    o[4] = u[4] * inv * g1.x + b1.x; o[5] = u[5] * inv * g1.y + b1.y;
    o[6] = u[6] * inv * g1.z + b1.z; o[7] = u[7] * inv * g1.w + b1.w;
    *(float4*)(outp + hbase + t * 8)     = make_float4(o[0], o[1], o[2], o[3]);
    *(float4*)(outp + hbase + t * 8 + 4) = make_float4(o[4], o[5], o[6], o[7]);
    ushort4 c0 = make_ushort4(f2bf(o[0]), f2bf(o[1]), f2bf(o[2]), f2bf(o[3]));
    ushort4 c1 = make_ushort4(f2bf(o[4]), f2bf(o[5]), f2bf(o[6]), f2bf(o[7]));
    *(ushort4*)(hb_out + hbase + t * 8)     = c0;
    *(ushort4*)(hb_out + hbase + t * 8 + 4) = c1;
  }
}

// ---------------- workspace layout (float offsets, all 16B-aligned) ----------------
#define OFF_H      ((size_t)0)            // N*128
#define OFF_SKIP   ((size_t)2560000)      // N*128
#define OFF_QKVB   ((size_t)6400000)      // N*1536 bf16
#define OFF_HB     ((size_t)21760000)     // N*128 bf16
#define OFF_XB     ((size_t)23040000)     // N*64 bf16
#define OFF_WT     ((size_t)23680000)     // 1664*128 bf16
#define OFF_WINT   ((size_t)23786496)     // 128*64 bf16
#define OFF_BCAT   ((size_t)23790592)     // 1664
#define OFF_CSRC   ((size_t)23792256)     // E ints
#define OFF_ROW    ((size_t)24112256)     // N+1 ints
#define OFF_DEG    ((size_t)24132260)     // N ints
#define OFF_CUR    ((size_t)24152260)     // N ints

extern "C" void kernel_launch(void* const* d_in, const int* in_sizes, int n_in,
                              void* d_out, int out_size, void* d_ws, size_t ws_size,
                              hipStream_t stream) {
  const float* x    = (const float*)d_in[0];
  const int*   ei   = (const int*)d_in[1];
  const float* Win  = (const float*)d_in[2];
  const float* bin_ = (const float*)d_in[3];
  const float* Wq   = (const float*)d_in[4];
  const float* bq   = (const float*)d_in[5];
  const float* Wk   = (const float*)d_in[6];
  const float* bk   = (const float*)d_in[7];
  const float* Wv   = (const float*)d_in[8];
  const float* bv   = (const float*)d_in[9];
  const float* Wsk  = (const float*)d_in[10];
  const float* bsk  = (const float*)d_in[11];
  const float* lng  = (const float*)d_in[12];
  const float* lnb  = (const float*)d_in[13];
  float* out = (float*)d_out;
  float* ws = (float*)d_ws;

  float* h     = ws + OFF_H;
  float* skipb = ws + OFF_SKIP;
  unsigned short* qkvb = (unsigned short*)(ws + OFF_QKVB);
  unsigned short* hb   = (unsigned short*)(ws + OFF_HB);
  unsigned short* xb   = (unsigned short*)(ws + OFF_XB);
  unsigned short* wT   = (unsigned short*)(ws + OFF_WT);
  unsigned short* winT = (unsigned short*)(ws + OFF_WINT);
  float* bcat  = ws + OFF_BCAT;
  int* csrc     = (int*)(ws + OFF_CSRC);
  int* rowstart = (int*)(ws + OFF_ROW);
  int* deg      = (int*)(ws + OFF_DEG);
  int* cur      = (int*)(ws + OFF_CUR);

  // ---- CSR build ----
  hipMemsetAsync(deg, 0, NN * sizeof(int), stream);
  hipMemsetAsync(cur, 0, NN * sizeof(int), stream);
  deg_hist<<<(EE + 255) / 256, 256, 0, stream>>>(ei, deg);
  scan_deg<<<1, 1024, 0, stream>>>(deg, rowstart);
  csr_scatter<<<(EE + 255) / 256, 256, 0, stream>>>(ei, rowstart, cur, csrc);

  // ---- input projection via MFMA (K=64): h fp32 + hb bf16 ----
  conv_x<<<(NN * DIN / 4 + 255) / 256, 256, 0, stream>>>(x, xb);
  build_winT<<<(HIDC * DIN + 255) / 256, 256, 0, stream>>>(Win, winT);
  {
    dim3 g(1, (NN + 127) / 128);
    mfma_gemm_t<64, 1><<<g, 256, 0, stream>>>(xb, winT, bin_, hb, h);
  }

  for (int l = 0; l < NL; ++l) {
    build_wcatT<<<(NCOLS * HIDC + 255) / 256, 256, 0, stream>>>(
        Wq + (size_t)l * HIDC * 512, Wk + (size_t)l * HIDC * 512,
        Wv + (size_t)l * HIDC * 512, Wsk + (size_t)l * HIDC * HIDC, wT);
    build_bcat<<<(NCOLS + 255) / 256, 256, 0, stream>>>(
        bq + (size_t)l * 512, bk + (size_t)l * 512, bv + (size_t)l * 512,
        bsk + (size_t)l * 128, bcat);

    {
      dim3 g(NCOLS / 128, (NN + 127) / 128);
      mfma_gemm_t<128, 0><<<g, 256, 0, stream>>>(hb, wT, bcat, qkvb, skipb);
    }

    float* dst = (l == NL - 1) ? out : h;
    node_fused<<<(NN + 3) / 4, 256, 0, stream>>>(
        qkvb, skipb, h, rowstart, csrc,
        lng + (size_t)l * 128, lnb + (size_t)l * 128, dst, hb);
  }
  (void)in_sizes; (void)n_in; (void)out_size; (void)ws_size;
}

// Round 6
// 333.863 us; speedup vs baseline: 13.6871x; 1.3961x over previous
//
#include <hip/hip_runtime.h>
#include <hip/hip_bf16.h>
#include <math.h>

#define NN 20000
#define EE 320000
#define DIN 64
#define HIDC 128
#define NCOLS 1664   // 512 q | 1024 kv(fp8) | 128 skip
#define NL 3

typedef __attribute__((ext_vector_type(8))) short bf16x8;
typedef __attribute__((ext_vector_type(8))) unsigned short u16x8;
typedef __attribute__((ext_vector_type(4))) float f32x4;

__device__ __forceinline__ float bf2f(unsigned short u) {
  union { unsigned i; float f; } v; v.i = ((unsigned)u) << 16; return v.f;
}
__device__ __forceinline__ unsigned short f2bf(float f) {
  __hip_bfloat16 b = __float2bfloat16(f);
  return *(unsigned short*)&b;
}

// ---- fp8 e4m3fn (OCP) encode/decode, HW cvt when available ----
__device__ __forceinline__ unsigned char f2fp8(float f) {
#if __has_builtin(__builtin_amdgcn_cvt_pk_fp8_f32)
  return (unsigned char)(__builtin_amdgcn_cvt_pk_fp8_f32(f, f, 0, 0) & 0xFF);
#else
  unsigned b = __float_as_uint(f);
  unsigned s = (b >> 24) & 0x80u;
  float a = fabsf(f);
  if (a < 0.015625f) return (unsigned char)s;      // flush subnormal
  unsigned mag = __float_as_uint(fminf(a, 448.f));
  mag += 0x7FFFFu + ((mag >> 20) & 1u);            // RNE at bit20
  unsigned code = (mag >> 20) - (120u << 3);
  if (code > 0x7Eu) code = 0x7Eu;
  return (unsigned char)(s | code);
#endif
}

__device__ __forceinline__ float fp82f(unsigned b) {
  unsigned x = ((b & 0x80u) << 24) | ((b & 0x7fu) << 20);
  return __uint_as_float(x) * 0x1p+120f;
}

// decode 8 fp8 (uint2) -> 8 floats
__device__ __forceinline__ void dec8(uint2 u, float* f) {
#if __has_builtin(__builtin_amdgcn_cvt_pk_f32_fp8)
  {
    auto p0 = __builtin_amdgcn_cvt_pk_f32_fp8(u.x, 0);
    auto p1 = __builtin_amdgcn_cvt_pk_f32_fp8(u.x, 1);
    auto p2 = __builtin_amdgcn_cvt_pk_f32_fp8(u.y, 0);
    auto p3 = __builtin_amdgcn_cvt_pk_f32_fp8(u.y, 1);
    f[0] = p0[0]; f[1] = p0[1]; f[2] = p1[0]; f[3] = p1[1];
    f[4] = p2[0]; f[5] = p2[1]; f[6] = p3[0]; f[7] = p3[1];
  }
#else
#pragma unroll
  for (int i = 0; i < 4; i++) f[i] = fp82f((u.x >> (8 * i)) & 0xFFu);
#pragma unroll
  for (int i = 0; i < 4; i++) f[4 + i] = fp82f((u.y >> (8 * i)) & 0xFFu);
#endif
}

// ---------------- weight/bias/input prep ----------------
__global__ void build_wcatT(const float* __restrict__ Wq, const float* __restrict__ Wk,
                            const float* __restrict__ Wv, const float* __restrict__ Wsk,
                            unsigned short* __restrict__ wT) {
  int idx = blockIdx.x * 256 + threadIdx.x;
  if (idx >= NCOLS * HIDC) return;
  int n = idx >> 7, k = idx & 127;
  float v;
  if (n < 512)       v = Wq[(size_t)k * 512 + n];
  else if (n < 1024) v = Wk[(size_t)k * 512 + (n - 512)];
  else if (n < 1536) v = Wv[(size_t)k * 512 + (n - 1024)];
  else               v = Wsk[(size_t)k * 128 + (n - 1536)];
  wT[idx] = f2bf(v);
}

__global__ void build_winT(const float* __restrict__ Win, unsigned short* __restrict__ winT) {
  int idx = blockIdx.x * 256 + threadIdx.x;
  if (idx >= HIDC * DIN) return;
  int c = idx >> 6, k = idx & 63;
  winT[idx] = f2bf(Win[(size_t)k * HIDC + c]);
}

__global__ void build_bcat(const float* __restrict__ bq, const float* __restrict__ bk,
                           const float* __restrict__ bv, const float* __restrict__ bsk,
                           float* __restrict__ bcat) {
  int m = blockIdx.x * 256 + threadIdx.x;
  if (m >= NCOLS) return;
  float v;
  if (m < 512)       v = bq[m];
  else if (m < 1024) v = bk[m - 512];
  else if (m < 1536) v = bv[m - 1024];
  else               v = bsk[m - 1536];
  bcat[m] = v;
}

__global__ void conv_x(const float* __restrict__ x, unsigned short* __restrict__ xb) {
  int i = blockIdx.x * 256 + threadIdx.x;
  if (i * 4 >= NN * DIN) return;
  float4 v = *(const float4*)(x + (size_t)i * 4);
  ushort4 o = make_ushort4(f2bf(v.x), f2bf(v.y), f2bf(v.z), f2bf(v.w));
  *(ushort4*)(xb + (size_t)i * 4) = o;
}

// ---------------- CSR build ----------------
__global__ void deg_hist(const int* __restrict__ ei, int* __restrict__ deg) {
  int e = blockIdx.x * 256 + threadIdx.x;
  if (e >= EE) return;
  atomicAdd(&deg[ei[EE + e]], 1);
}

__global__ __launch_bounds__(1024) void scan_deg(const int* __restrict__ deg,
                                                 int* __restrict__ rowstart) {
  __shared__ int part[1024];
  int t = threadIdx.x;
  int base = t * 20;
  int local[20];
  int s = 0;
#pragma unroll
  for (int i = 0; i < 20; i++) {
    int idx = base + i;
    int d = (idx < NN) ? deg[idx] : 0;
    local[i] = d;
    s += d;
  }
  part[t] = s;
  __syncthreads();
  for (int d = 1; d < 1024; d <<= 1) {
    int v = (t >= d) ? part[t - d] : 0;
    __syncthreads();
    part[t] += v;
    __syncthreads();
  }
  int run = part[t] - s;
#pragma unroll
  for (int i = 0; i < 20; i++) {
    int idx = base + i;
    if (idx < NN) rowstart[idx] = run;
    run += local[i];
  }
  if (t == 1023) rowstart[NN] = part[1023];
}

__global__ void csr_scatter(const int* __restrict__ ei, const int* __restrict__ rowstart,
                            int* __restrict__ cur, int* __restrict__ csrc) {
  int e = blockIdx.x * 256 + threadIdx.x;
  if (e >= EE) return;
  int src = ei[e], dst = ei[EE + e];
  int pos = atomicAdd(&cur[dst], 1);
  csrc[rowstart[dst] + pos] = src;
}

// ---------------- tiled MFMA GEMM (BM=BN=128) ----------------
__device__ __forceinline__ void gl_lds16(const void* g, void* l) {
  __builtin_amdgcn_global_load_lds((const unsigned int*)g, (unsigned int*)l, 16, 0, 0);
}

template <int K>
__device__ __forceinline__ void stage_tile(const unsigned short* gbase,
                                           unsigned char* lbase, int tid) {
  constexpr int CH = K / 8;
  constexpr int ISS = (128 * CH) / 256;
  int wave = tid >> 6;
#pragma unroll
  for (int p = 0; p < ISS; p++) {
    int slot = p * 256 + tid;
    int row = slot / CH, ch = slot % CH;
    const unsigned short* src = gbase + (size_t)row * K + ((ch ^ (row & 7)) * 8);
    unsigned char* ldst = lbase + (size_t)(p * 256 + wave * 64) * 16;
    gl_lds16(src, ldst);
  }
}

template <int K>
__device__ __forceinline__ bf16x8 read_frag(const unsigned char* lbase, int row, int kk, int lk) {
  int ch = (kk * 4 + lk) ^ (row & 7);
  return *(const bf16x8*)(lbase + (size_t)row * (K * 2) + ch * 16);
}

// MODE 0: A=hb[NN][128], BT=wT[1664][128].
//   bx 0-3  -> q cols 0-511   -> bf16 to qb [NN][512]
//   bx 4-11 -> kv cols 512-1535 -> fp8 to kv8 [NN][1024]
//   bx 12   -> skip cols       -> fp32 to skipb [NN][128]
// MODE 1: A=xb[NN][64], BT=winT[128][64]; fp32 to h AND bf16 to hb
template <int K, int MODE>
__global__ __launch_bounds__(256) void mfma_gemm_t(
    const unsigned short* __restrict__ A, const unsigned short* __restrict__ BT,
    const float* __restrict__ bias, unsigned short* __restrict__ outb,
    unsigned char* __restrict__ outkv, float* __restrict__ outf) {
  constexpr int LDSZ = (512 * K > 34816) ? 512 * K : 34816;
  __shared__ __align__(16) unsigned char LDS[LDSZ];
  const int tid = threadIdx.x;
  const int lane = tid & 63;
  const int wave = tid >> 6;
  const int lm = lane & 15, lk = lane >> 4;
  const int wm = wave >> 1, wn = wave & 1;
  const int row0 = blockIdx.y * 128, col0 = blockIdx.x * 128;
  unsigned char* aL = LDS;
  unsigned char* bL = LDS + 128 * K * 2;

  stage_tile<K>(A + (size_t)row0 * K, aL, tid);
  stage_tile<K>(BT + (size_t)col0 * K, bL, tid);
  __syncthreads();

  constexpr int KK = K / 32;
  f32x4 acc[4][4] = {};
  bf16x8 af[4][KK];
#pragma unroll
  for (int mf = 0; mf < 4; mf++)
#pragma unroll
    for (int kk = 0; kk < KK; kk++)
      af[mf][kk] = read_frag<K>(aL, wm * 64 + mf * 16 + lm, kk, lk);

#pragma unroll
  for (int nf = 0; nf < 4; nf++) {
    bf16x8 bf[KK];
#pragma unroll
    for (int kk = 0; kk < KK; kk++)
      bf[kk] = read_frag<K>(bL, wn * 64 + nf * 16 + lm, kk, lk);
#pragma unroll
    for (int mf = 0; mf < 4; mf++)
#pragma unroll
      for (int kk = 0; kk < KK; kk++)
        acc[mf][nf] = __builtin_amdgcn_mfma_f32_16x16x32_bf16(af[mf][kk], bf[kk],
                                                              acc[mf][nf], 0, 0, 0);
  }
  __syncthreads();

  if (MODE == 0 && blockIdx.x == 12) {
    // skip tile: fp32 direct
#pragma unroll
    for (int nf = 0; nf < 4; nf++) {
      int c = wn * 64 + nf * 16 + lm;
      float bv = bias[col0 + c];
#pragma unroll
      for (int mf = 0; mf < 4; mf++)
#pragma unroll
        for (int i = 0; i < 4; i++) {
          int r = row0 + wm * 64 + mf * 16 + lk * 4 + i;
          if (r < NN) outf[(size_t)r * HIDC + c] = acc[mf][nf][i] + bv;
        }
    }
  } else if (MODE == 0 && blockIdx.x >= 4) {
    // fp8 kv bounce: LDS [128][144] bytes
    unsigned char* bb8 = LDS;
#pragma unroll
    for (int nf = 0; nf < 4; nf++) {
      int c = wn * 64 + nf * 16 + lm;
      float bv = bias[col0 + c];
#pragma unroll
      for (int mf = 0; mf < 4; mf++)
#pragma unroll
        for (int i = 0; i < 4; i++) {
          int row = wm * 64 + mf * 16 + lk * 4 + i;
          bb8[row * 144 + c] = f2fp8(acc[mf][nf][i] + bv);
        }
    }
    __syncthreads();
    const int kvcol0 = col0 - 512;
#pragma unroll
    for (int p = 0; p < 4; p++) {
      int idx = p * 256 + tid;
      int row = idx >> 3, cw = idx & 7;
      int gr = row0 + row;
      if (gr < NN) {
        uint4 v = *(const uint4*)(bb8 + row * 144 + cw * 16);
        *(uint4*)(outkv + (size_t)gr * 1024 + kvcol0 + cw * 16) = v;
      }
    }
  } else {
    // bf16 bounce: LDS [128][136] shorts
    unsigned short* bb = (unsigned short*)LDS;
#pragma unroll
    for (int nf = 0; nf < 4; nf++) {
      int c = wn * 64 + nf * 16 + lm;
      float bv = bias[col0 + c];
#pragma unroll
      for (int mf = 0; mf < 4; mf++)
#pragma unroll
        for (int i = 0; i < 4; i++) {
          int row = wm * 64 + mf * 16 + lk * 4 + i;
          bb[row * 136 + c] = f2bf(acc[mf][nf][i] + bv);
          if (MODE == 1) {
            int r = row0 + row;
            if (r < NN) outf[(size_t)r * HIDC + c] = acc[mf][nf][i] + bv;
          }
        }
    }
    __syncthreads();
    constexpr int STRIDE = (MODE == 0) ? 512 : HIDC;
#pragma unroll
    for (int p = 0; p < 8; p++) {
      int idx = p * 256 + tid;
      int row = idx >> 4, c = idx & 15;
      int gr = row0 + row;
      if (gr < NN) {
        uint4 v = *(const uint4*)(bb + row * 136 + c * 8);
        *(uint4*)(outb + (size_t)gr * STRIDE + col0 + c * 8) = v;
      }
    }
  }
}

// ---------------- fused single-pass flash-style node kernel (fp8 k/v) ----------------
// one wave per node; lane = hh*16 + t (head hh, dims t*8..t*8+7)
__global__ __launch_bounds__(256) void node_fused(
    const unsigned short* __restrict__ qb, const unsigned char* __restrict__ kv8,
    const float* __restrict__ skipb,
    const float* __restrict__ h, const int* __restrict__ rowstart,
    const int* __restrict__ csrc,
    const float* __restrict__ gamma, const float* __restrict__ beta,
    float* __restrict__ outp, unsigned short* __restrict__ hb_out) {
  int n = blockIdx.x * 4 + (threadIdx.x >> 6);
  if (n >= NN) return;
  int lane = threadIdx.x & 63;
  int hh = lane >> 4, t = lane & 15;
  int j0 = rowstart[n], j1 = rowstart[n + 1];

  // q fragment in registers (bf16)
  u16x8 q8 = *(const u16x8*)(qb + (size_t)n * 512 + hh * 128 + t * 8);
  float qf[8];
#pragma unroll
  for (int i = 0; i < 8; i++) qf[i] = bf2f(q8[i]);

  const unsigned char* kb = kv8 + hh * 128 + t * 8;        // k: bytes 0..511
  const unsigned char* vb = kv8 + 512 + hh * 128 + t * 8;  // v: bytes 512..1023

  float m = -INFINITY, s = 0.f;
  float acc[8] = {0.f, 0.f, 0.f, 0.f, 0.f, 0.f, 0.f, 0.f};

  int j = j0;
  for (; j + 1 < j1; j += 2) {
    int sA = csrc[j], sB = csrc[j + 1];
    uint2 kA = *(const uint2*)(kb + (size_t)sA * 1024);
    uint2 vA = *(const uint2*)(vb + (size_t)sA * 1024);
    uint2 kB = *(const uint2*)(kb + (size_t)sB * 1024);
    uint2 vB = *(const uint2*)(vb + (size_t)sB * 1024);
    float kfA[8], kfB[8];
    dec8(kA, kfA); dec8(kB, kfB);
    float pA = 0.f, pB = 0.f;
#pragma unroll
    for (int i = 0; i < 8; i++) { pA += qf[i] * kfA[i]; pB += qf[i] * kfB[i]; }
    pA += __shfl_xor(pA, 1); pB += __shfl_xor(pB, 1);
    pA += __shfl_xor(pA, 2); pB += __shfl_xor(pB, 2);
    pA += __shfl_xor(pA, 4); pB += __shfl_xor(pB, 4);
    pA += __shfl_xor(pA, 8); pB += __shfl_xor(pB, 8);
    float lgA = pA * 0.08838834764831845f;
    float lgB = pB * 0.08838834764831845f;
    float vfA[8], vfB[8];
    dec8(vA, vfA); dec8(vB, vfB);
    if (lgA > m) {
      float r = __expf(m - lgA);
      s *= r;
#pragma unroll
      for (int i = 0; i < 8; i++) acc[i] *= r;
      m = lgA;
    }
    float wA = __expf(lgA - m);
    s += wA;
#pragma unroll
    for (int i = 0; i < 8; i++) acc[i] += wA * vfA[i];
    if (lgB > m) {
      float r = __expf(m - lgB);
      s *= r;
#pragma unroll
      for (int i = 0; i < 8; i++) acc[i] *= r;
      m = lgB;
    }
    float wB = __expf(lgB - m);
    s += wB;
#pragma unroll
    for (int i = 0; i < 8; i++) acc[i] += wB * vfB[i];
  }
  if (j < j1) {
    int sA = csrc[j];
    uint2 kA = *(const uint2*)(kb + (size_t)sA * 1024);
    uint2 vA = *(const uint2*)(vb + (size_t)sA * 1024);
    float kfA[8], vfA[8];
    dec8(kA, kfA); dec8(vA, vfA);
    float pA = 0.f;
#pragma unroll
    for (int i = 0; i < 8; i++) pA += qf[i] * kfA[i];
    pA += __shfl_xor(pA, 1);
    pA += __shfl_xor(pA, 2);
    pA += __shfl_xor(pA, 4);
    pA += __shfl_xor(pA, 8);
    float lgA = pA * 0.08838834764831845f;
    if (lgA > m) {
      float r = __expf(m - lgA);
      s *= r;
#pragma unroll
      for (int i = 0; i < 8; i++) acc[i] *= r;
      m = lgA;
    }
    float wA = __expf(lgA - m);
    s += wA;
#pragma unroll
    for (int i = 0; i < 8; i++) acc[i] += wA * vfA[i];
  }

  // normalize + head-mean fold, sum across the 4 head groups
  float rsel = 0.25f / (s + 1e-16f);
#pragma unroll
  for (int i = 0; i < 8; i++) {
    float a = acc[i] * rsel;
    a += __shfl_xor(a, 16);
    a += __shfl_xor(a, 32);
    acc[i] = a;
  }

  // finalize: u = h + aggr + skip; LayerNorm over 128 dims
  size_t hbase = (size_t)n * HIDC;
  float u[8];
  {
    float4 h0 = *(const float4*)(h + hbase + t * 8);
    float4 h1 = *(const float4*)(h + hbase + t * 8 + 4);
    float4 k0 = *(const float4*)(skipb + hbase + t * 8);
    float4 k1 = *(const float4*)(skipb + hbase + t * 8 + 4);
    u[0] = h0.x + acc[0] + k0.x; u[1] = h0.y + acc[1] + k0.y;
    u[2] = h0.z + acc[2] + k0.z; u[3] = h0.w + acc[3] + k0.w;
    u[4] = h1.x + acc[4] + k1.x; u[5] = h1.y + acc[5] + k1.y;
    u[6] = h1.z + acc[6] + k1.z; u[7] = h1.w + acc[7] + k1.w;
  }
  float su = 0.f;
#pragma unroll
  for (int i = 0; i < 8; i++) su += u[i];
#pragma unroll
  for (int d = 1; d < 16; d <<= 1) su += __shfl_xor(su, d);
  float mu = su * (1.f / 128.f);
  float vs = 0.f;
#pragma unroll
  for (int i = 0; i < 8; i++) { u[i] -= mu; vs += u[i] * u[i]; }
#pragma unroll
  for (int d = 1; d < 16; d <<= 1) vs += __shfl_xor(vs, d);
  float inv = rsqrtf(vs * (1.f / 128.f) + 1e-5f);
  if (hh == 0) {
    float4 g0 = *(const float4*)(gamma + t * 8);
    float4 g1 = *(const float4*)(gamma + t * 8 + 4);
    float4 b0 = *(const float4*)(beta + t * 8);
    float4 b1 = *(const float4*)(beta + t * 8 + 4);
    float o[8];
    o[0] = u[0] * inv * g0.x + b0.x; o[1] = u[1] * inv * g0.y + b0.y;
    o[2] = u[2] * inv * g0.z + b0.z; o[3] = u[3] * inv * g0.w + b0.w;
    o[4] = u[4] * inv * g1.x + b1.x; o[5] = u[5] * inv * g1.y + b1.y;
    o[6] = u[6] * inv * g1.z + b1.z; o[7] = u[7] * inv * g1.w + b1.w;
    *(float4*)(outp + hbase + t * 8)     = make_float4(o[0], o[1], o[2], o[3]);
    *(float4*)(outp + hbase + t * 8 + 4) = make_float4(o[4], o[5], o[6], o[7]);
    ushort4 c0 = make_ushort4(f2bf(o[0]), f2bf(o[1]), f2bf(o[2]), f2bf(o[3]));
    ushort4 c1 = make_ushort4(f2bf(o[4]), f2bf(o[5]), f2bf(o[6]), f2bf(o[7]));
    *(ushort4*)(hb_out + hbase + t * 8)     = c0;
    *(ushort4*)(hb_out + hbase + t * 8 + 4) = c1;
  }
}

// ---------------- workspace layout (float offsets, all 16B-aligned) ----------------
#define OFF_H      ((size_t)0)            // N*128 fp32
#define OFF_SKIP   ((size_t)2560000)      // N*128 fp32
#define OFF_QB     ((size_t)5120000)      // N*512 bf16
#define OFF_KV8    ((size_t)10240000)     // N*1024 fp8
#define OFF_HB     ((size_t)15360000)     // N*128 bf16
#define OFF_XB     ((size_t)16640000)     // N*64 bf16
#define OFF_WT     ((size_t)17280000)     // 1664*128 bf16
#define OFF_WINT   ((size_t)17386496)     // 128*64 bf16
#define OFF_BCAT   ((size_t)17390592)     // 1664 fp32
#define OFF_CSRC   ((size_t)17392256)     // E ints
#define OFF_ROW    ((size_t)17712256)     // N+1 ints
#define OFF_DEG    ((size_t)17732260)     // N ints
#define OFF_CUR    ((size_t)17752260)     // N ints
// end ~17.77M floats ~= 71 MB

extern "C" void kernel_launch(void* const* d_in, const int* in_sizes, int n_in,
                              void* d_out, int out_size, void* d_ws, size_t ws_size,
                              hipStream_t stream) {
  const float* x    = (const float*)d_in[0];
  const int*   ei   = (const int*)d_in[1];
  const float* Win  = (const float*)d_in[2];
  const float* bin_ = (const float*)d_in[3];
  const float* Wq   = (const float*)d_in[4];
  const float* bq   = (const float*)d_in[5];
  const float* Wk   = (const float*)d_in[6];
  const float* bk   = (const float*)d_in[7];
  const float* Wv   = (const float*)d_in[8];
  const float* bv   = (const float*)d_in[9];
  const float* Wsk  = (const float*)d_in[10];
  const float* bsk  = (const float*)d_in[11];
  const float* lng  = (const float*)d_in[12];
  const float* lnb  = (const float*)d_in[13];
  float* out = (float*)d_out;
  float* ws = (float*)d_ws;

  float* h     = ws + OFF_H;
  float* skipb = ws + OFF_SKIP;
  unsigned short* qb   = (unsigned short*)(ws + OFF_QB);
  unsigned char*  kv8  = (unsigned char*)(ws + OFF_KV8);
  unsigned short* hb   = (unsigned short*)(ws + OFF_HB);
  unsigned short* xb   = (unsigned short*)(ws + OFF_XB);
  unsigned short* wT   = (unsigned short*)(ws + OFF_WT);
  unsigned short* winT = (unsigned short*)(ws + OFF_WINT);
  float* bcat  = ws + OFF_BCAT;
  int* csrc     = (int*)(ws + OFF_CSRC);
  int* rowstart = (int*)(ws + OFF_ROW);
  int* deg      = (int*)(ws + OFF_DEG);
  int* cur      = (int*)(ws + OFF_CUR);

  // ---- CSR build ----
  hipMemsetAsync(deg, 0, NN * sizeof(int), stream);
  hipMemsetAsync(cur, 0, NN * sizeof(int), stream);
  deg_hist<<<(EE + 255) / 256, 256, 0, stream>>>(ei, deg);
  scan_deg<<<1, 1024, 0, stream>>>(deg, rowstart);
  csr_scatter<<<(EE + 255) / 256, 256, 0, stream>>>(ei, rowstart, cur, csrc);

  // ---- input projection via MFMA (K=64): h fp32 + hb bf16 ----
  conv_x<<<(NN * DIN / 4 + 255) / 256, 256, 0, stream>>>(x, xb);
  build_winT<<<(HIDC * DIN + 255) / 256, 256, 0, stream>>>(Win, winT);
  {
    dim3 g(1, (NN + 127) / 128);
    mfma_gemm_t<64, 1><<<g, 256, 0, stream>>>(xb, winT, bin_, hb, kv8, h);
  }

  for (int l = 0; l < NL; ++l) {
    build_wcatT<<<(NCOLS * HIDC + 255) / 256, 256, 0, stream>>>(
        Wq + (size_t)l * HIDC * 512, Wk + (size_t)l * HIDC * 512,
        Wv + (size_t)l * HIDC * 512, Wsk + (size_t)l * HIDC * HIDC, wT);
    build_bcat<<<(NCOLS + 255) / 256, 256, 0, stream>>>(
        bq + (size_t)l * 512, bk + (size_t)l * 512, bv + (size_t)l * 512,
        bsk + (size_t)l * 128, bcat);

    {
      dim3 g(NCOLS / 128, (NN + 127) / 128);
      mfma_gemm_t<128, 0><<<g, 256, 0, stream>>>(hb, wT, bcat, qb, kv8, skipb);
    }

    float* dst = (l == NL - 1) ? out : h;
    node_fused<<<(NN + 3) / 4, 256, 0, stream>>>(
        qb, kv8, skipb, h, rowstart, csrc,
        lng + (size_t)l * 128, lnb + (size_t)l * 128, dst, hb);
  }
  (void)in_sizes; (void)n_in; (void)out_size; (void)ws_size;
}

// Round 7
// 331.256 us; speedup vs baseline: 13.7948x; 1.0079x over previous
//
#include <hip/hip_runtime.h>
#include <hip/hip_bf16.h>
#include <math.h>

#define NN 20000
#define EE 320000
#define DIN 64
#define HIDC 128
#define NCOLS 1664   // 512 q | 1024 kv(fp8) | 128 skip
#define NL 3

typedef __attribute__((ext_vector_type(8))) short bf16x8;
typedef __attribute__((ext_vector_type(8))) unsigned short u16x8;
typedef __attribute__((ext_vector_type(4))) float f32x4;

__device__ __forceinline__ float bf2f(unsigned short u) {
  union { unsigned i; float f; } v; v.i = ((unsigned)u) << 16; return v.f;
}
__device__ __forceinline__ unsigned short f2bf(float f) {
  __hip_bfloat16 b = __float2bfloat16(f);
  return *(unsigned short*)&b;
}

// ---- fp8 e4m3fn (OCP) encode/decode, HW cvt when available ----
__device__ __forceinline__ unsigned char f2fp8(float f) {
#if __has_builtin(__builtin_amdgcn_cvt_pk_fp8_f32)
  return (unsigned char)(__builtin_amdgcn_cvt_pk_fp8_f32(f, f, 0, 0) & 0xFF);
#else
  unsigned b = __float_as_uint(f);
  unsigned s = (b >> 24) & 0x80u;
  float a = fabsf(f);
  if (a < 0.015625f) return (unsigned char)s;
  unsigned mag = __float_as_uint(fminf(a, 448.f));
  mag += 0x7FFFFu + ((mag >> 20) & 1u);
  unsigned code = (mag >> 20) - (120u << 3);
  if (code > 0x7Eu) code = 0x7Eu;
  return (unsigned char)(s | code);
#endif
}

__device__ __forceinline__ float fp82f(unsigned b) {
  unsigned x = ((b & 0x80u) << 24) | ((b & 0x7fu) << 20);
  return __uint_as_float(x) * 0x1p+120f;
}

__device__ __forceinline__ void dec8(uint2 u, float* f) {
#if __has_builtin(__builtin_amdgcn_cvt_pk_f32_fp8)
  {
    auto p0 = __builtin_amdgcn_cvt_pk_f32_fp8(u.x, 0);
    auto p1 = __builtin_amdgcn_cvt_pk_f32_fp8(u.x, 1);
    auto p2 = __builtin_amdgcn_cvt_pk_f32_fp8(u.y, 0);
    auto p3 = __builtin_amdgcn_cvt_pk_f32_fp8(u.y, 1);
    f[0] = p0[0]; f[1] = p0[1]; f[2] = p1[0]; f[3] = p1[1];
    f[4] = p2[0]; f[5] = p2[1]; f[6] = p3[0]; f[7] = p3[1];
  }
#else
#pragma unroll
  for (int i = 0; i < 4; i++) f[i] = fp82f((u.x >> (8 * i)) & 0xFFu);
#pragma unroll
  for (int i = 0; i < 4; i++) f[4 + i] = fp82f((u.y >> (8 * i)) & 0xFFu);
#endif
}

// ---------------- weight/bias/input prep ----------------
__global__ void build_wcatT(const float* __restrict__ Wq, const float* __restrict__ Wk,
                            const float* __restrict__ Wv, const float* __restrict__ Wsk,
                            unsigned short* __restrict__ wT) {
  int idx = blockIdx.x * 256 + threadIdx.x;
  if (idx >= NCOLS * HIDC) return;
  int n = idx >> 7, k = idx & 127;
  float v;
  if (n < 512)       v = Wq[(size_t)k * 512 + n];
  else if (n < 1024) v = Wk[(size_t)k * 512 + (n - 512)];
  else if (n < 1536) v = Wv[(size_t)k * 512 + (n - 1024)];
  else               v = Wsk[(size_t)k * 128 + (n - 1536)];
  wT[idx] = f2bf(v);
}

__global__ void build_winT(const float* __restrict__ Win, unsigned short* __restrict__ winT) {
  int idx = blockIdx.x * 256 + threadIdx.x;
  if (idx >= HIDC * DIN) return;
  int c = idx >> 6, k = idx & 63;
  winT[idx] = f2bf(Win[(size_t)k * HIDC + c]);
}

__global__ void build_bcat(const float* __restrict__ bq, const float* __restrict__ bk,
                           const float* __restrict__ bv, const float* __restrict__ bsk,
                           float* __restrict__ bcat) {
  int m = blockIdx.x * 256 + threadIdx.x;
  if (m >= NCOLS) return;
  float v;
  if (m < 512)       v = bq[m];
  else if (m < 1024) v = bk[m - 512];
  else if (m < 1536) v = bv[m - 1024];
  else               v = bsk[m - 1536];
  bcat[m] = v;
}

__global__ void conv_x(const float* __restrict__ x, unsigned short* __restrict__ xb) {
  int i = blockIdx.x * 256 + threadIdx.x;
  if (i * 4 >= NN * DIN) return;
  float4 v = *(const float4*)(x + (size_t)i * 4);
  ushort4 o = make_ushort4(f2bf(v.x), f2bf(v.y), f2bf(v.z), f2bf(v.w));
  *(ushort4*)(xb + (size_t)i * 4) = o;
}

// ---------------- CSR build ----------------
__global__ void deg_hist(const int* __restrict__ ei, int* __restrict__ deg) {
  int e = blockIdx.x * 256 + threadIdx.x;
  if (e >= EE) return;
  atomicAdd(&deg[ei[EE + e]], 1);
}

__global__ __launch_bounds__(1024) void scan_deg(const int* __restrict__ deg,
                                                 int* __restrict__ rowstart) {
  __shared__ int part[1024];
  int t = threadIdx.x;
  int base = t * 20;
  int local[20];
  int s = 0;
#pragma unroll
  for (int i = 0; i < 20; i++) {
    int idx = base + i;
    int d = (idx < NN) ? deg[idx] : 0;
    local[i] = d;
    s += d;
  }
  part[t] = s;
  __syncthreads();
  for (int d = 1; d < 1024; d <<= 1) {
    int v = (t >= d) ? part[t - d] : 0;
    __syncthreads();
    part[t] += v;
    __syncthreads();
  }
  int run = part[t] - s;
#pragma unroll
  for (int i = 0; i < 20; i++) {
    int idx = base + i;
    if (idx < NN) rowstart[idx] = run;
    run += local[i];
  }
  if (t == 1023) rowstart[NN] = part[1023];
}

__global__ void csr_scatter(const int* __restrict__ ei, const int* __restrict__ rowstart,
                            int* __restrict__ cur, int* __restrict__ csrc) {
  int e = blockIdx.x * 256 + threadIdx.x;
  if (e >= EE) return;
  int src = ei[e], dst = ei[EE + e];
  int pos = atomicAdd(&cur[dst], 1);
  csrc[rowstart[dst] + pos] = src;
}

// ---------------- tiled MFMA GEMM (BM=BN=128), XCD-chunk swizzled ----------------
__device__ __forceinline__ void gl_lds16(const void* g, void* l) {
  __builtin_amdgcn_global_load_lds((const unsigned int*)g, (unsigned int*)l, 16, 0, 0);
}

template <int K>
__device__ __forceinline__ void stage_tile(const unsigned short* gbase,
                                           unsigned char* lbase, int tid) {
  constexpr int CH = K / 8;
  constexpr int ISS = (128 * CH) / 256;
  int wave = tid >> 6;
#pragma unroll
  for (int p = 0; p < ISS; p++) {
    int slot = p * 256 + tid;
    int row = slot / CH, ch = slot % CH;
    const unsigned short* src = gbase + (size_t)row * K + ((ch ^ (row & 7)) * 8);
    unsigned char* ldst = lbase + (size_t)(p * 256 + wave * 64) * 16;
    gl_lds16(src, ldst);
  }
}

template <int K>
__device__ __forceinline__ bf16x8 read_frag(const unsigned char* lbase, int row, int kk, int lk) {
  int ch = (kk * 4 + lk) ^ (row & 7);
  return *(const bf16x8*)(lbase + (size_t)row * (K * 2) + ch * 16);
}

// MODE 0: A=hb[NN][128], BT=wT[1664][128].
//   bx 0-3  -> q cols -> bf16 qb[NN][512]; bx 4-11 -> kv -> fp8 kv8[NN][1024];
//   bx 12   -> skip  -> fp32 skipb[NN][128]
// MODE 1: A=xb[NN][64], BT=winT[128][64]; fp32 h + bf16 hb
// 1D grid of nwg = nbx*nby blocks; bijective XCD-chunk swizzle (8 XCDs):
// XCD x processes a CONTIGUOUS run of logical tiles -> A-tile reuse stays in x's L2.
template <int K, int MODE>
__global__ __launch_bounds__(256) void mfma_gemm_t(
    const unsigned short* __restrict__ A, const unsigned short* __restrict__ BT,
    const float* __restrict__ bias, unsigned short* __restrict__ outb,
    unsigned char* __restrict__ outkv, float* __restrict__ outf,
    int nbx, int nwg) {
  constexpr int LDSZ = (512 * K > 34816) ? 512 * K : 34816;
  __shared__ __align__(16) unsigned char LDS[LDSZ];
  const int tid = threadIdx.x;

  // bijective XCD-chunk swizzle (m204): orig i -> xcd i&7, slot i>>3
  int orig = blockIdx.x;
  int q = nwg >> 3, r = nwg & 7;
  int xcd = orig & 7, slot = orig >> 3;
  int wg = (xcd < r ? xcd * (q + 1) : r * (q + 1) + (xcd - r) * q) + slot;
  const int bx = wg % nbx, by = wg / nbx;

  const int lane = tid & 63;
  const int wave = tid >> 6;
  const int lm = lane & 15, lk = lane >> 4;
  const int wm = wave >> 1, wn = wave & 1;
  const int row0 = by * 128, col0 = bx * 128;
  unsigned char* aL = LDS;
  unsigned char* bL = LDS + 128 * K * 2;

  stage_tile<K>(A + (size_t)row0 * K, aL, tid);
  stage_tile<K>(BT + (size_t)col0 * K, bL, tid);
  __syncthreads();

  constexpr int KK = K / 32;
  f32x4 acc[4][4] = {};
  bf16x8 af[4][KK];
#pragma unroll
  for (int mf = 0; mf < 4; mf++)
#pragma unroll
    for (int kk = 0; kk < KK; kk++)
      af[mf][kk] = read_frag<K>(aL, wm * 64 + mf * 16 + lm, kk, lk);

#pragma unroll
  for (int nf = 0; nf < 4; nf++) {
    bf16x8 bf[KK];
#pragma unroll
    for (int kk = 0; kk < KK; kk++)
      bf[kk] = read_frag<K>(bL, wn * 64 + nf * 16 + lm, kk, lk);
#pragma unroll
    for (int mf = 0; mf < 4; mf++)
#pragma unroll
      for (int kk = 0; kk < KK; kk++)
        acc[mf][nf] = __builtin_amdgcn_mfma_f32_16x16x32_bf16(af[mf][kk], bf[kk],
                                                              acc[mf][nf], 0, 0, 0);
  }
  __syncthreads();

  if (MODE == 0 && bx == 12) {
#pragma unroll
    for (int nf = 0; nf < 4; nf++) {
      int c = wn * 64 + nf * 16 + lm;
      float bv = bias[col0 + c];
#pragma unroll
      for (int mf = 0; mf < 4; mf++)
#pragma unroll
        for (int i = 0; i < 4; i++) {
          int rr = row0 + wm * 64 + mf * 16 + lk * 4 + i;
          if (rr < NN) outf[(size_t)rr * HIDC + c] = acc[mf][nf][i] + bv;
        }
    }
  } else if (MODE == 0 && bx >= 4) {
    unsigned char* bb8 = LDS;
#pragma unroll
    for (int nf = 0; nf < 4; nf++) {
      int c = wn * 64 + nf * 16 + lm;
      float bv = bias[col0 + c];
#pragma unroll
      for (int mf = 0; mf < 4; mf++)
#pragma unroll
        for (int i = 0; i < 4; i++) {
          int row = wm * 64 + mf * 16 + lk * 4 + i;
          bb8[row * 144 + c] = f2fp8(acc[mf][nf][i] + bv);
        }
    }
    __syncthreads();
    const int kvcol0 = col0 - 512;
#pragma unroll
    for (int p = 0; p < 4; p++) {
      int idx = p * 256 + tid;
      int row = idx >> 3, cw = idx & 7;
      int gr = row0 + row;
      if (gr < NN) {
        uint4 v = *(const uint4*)(bb8 + row * 144 + cw * 16);
        *(uint4*)(outkv + (size_t)gr * 1024 + kvcol0 + cw * 16) = v;
      }
    }
  } else {
    unsigned short* bb = (unsigned short*)LDS;
#pragma unroll
    for (int nf = 0; nf < 4; nf++) {
      int c = wn * 64 + nf * 16 + lm;
      float bv = bias[col0 + c];
#pragma unroll
      for (int mf = 0; mf < 4; mf++)
#pragma unroll
        for (int i = 0; i < 4; i++) {
          int row = wm * 64 + mf * 16 + lk * 4 + i;
          bb[row * 136 + c] = f2bf(acc[mf][nf][i] + bv);
          if (MODE == 1) {
            int rr = row0 + row;
            if (rr < NN) outf[(size_t)rr * HIDC + c] = acc[mf][nf][i] + bv;
          }
        }
    }
    __syncthreads();
    constexpr int STRIDE = (MODE == 0) ? 512 : HIDC;
#pragma unroll
    for (int p = 0; p < 8; p++) {
      int idx = p * 256 + tid;
      int row = idx >> 4, c = idx & 15;
      int gr = row0 + row;
      if (gr < NN) {
        uint4 v = *(const uint4*)(bb + row * 136 + c * 8);
        *(uint4*)(outb + (size_t)gr * STRIDE + col0 + c * 8) = v;
      }
    }
  }
}

// ---------------- fused single-pass flash-style node kernel (fp8 k/v) ----------------
__global__ __launch_bounds__(256) void node_fused(
    const unsigned short* __restrict__ qb, const unsigned char* __restrict__ kv8,
    const float* __restrict__ skipb,
    const float* __restrict__ h, const int* __restrict__ rowstart,
    const int* __restrict__ csrc,
    const float* __restrict__ gamma, const float* __restrict__ beta,
    float* __restrict__ outp, unsigned short* __restrict__ hb_out) {
  int n = blockIdx.x * 4 + (threadIdx.x >> 6);
  if (n >= NN) return;
  int lane = threadIdx.x & 63;
  int hh = lane >> 4, t = lane & 15;
  int j0 = rowstart[n], j1 = rowstart[n + 1];

  u16x8 q8 = *(const u16x8*)(qb + (size_t)n * 512 + hh * 128 + t * 8);
  float qf[8];
#pragma unroll
  for (int i = 0; i < 8; i++) qf[i] = bf2f(q8[i]);

  const unsigned char* kb = kv8 + hh * 128 + t * 8;
  const unsigned char* vb = kv8 + 512 + hh * 128 + t * 8;

  float m = -INFINITY, s = 0.f;
  float acc[8] = {0.f, 0.f, 0.f, 0.f, 0.f, 0.f, 0.f, 0.f};

  int j = j0;
  for (; j + 1 < j1; j += 2) {
    int sA = csrc[j], sB = csrc[j + 1];
    uint2 kA = *(const uint2*)(kb + (size_t)sA * 1024);
    uint2 vA = *(const uint2*)(vb + (size_t)sA * 1024);
    uint2 kB = *(const uint2*)(kb + (size_t)sB * 1024);
    uint2 vB = *(const uint2*)(vb + (size_t)sB * 1024);
    float kfA[8], kfB[8];
    dec8(kA, kfA); dec8(kB, kfB);
    float pA = 0.f, pB = 0.f;
#pragma unroll
    for (int i = 0; i < 8; i++) { pA += qf[i] * kfA[i]; pB += qf[i] * kfB[i]; }
    pA += __shfl_xor(pA, 1); pB += __shfl_xor(pB, 1);
    pA += __shfl_xor(pA, 2); pB += __shfl_xor(pB, 2);
    pA += __shfl_xor(pA, 4); pB += __shfl_xor(pB, 4);
    pA += __shfl_xor(pA, 8); pB += __shfl_xor(pB, 8);
    float lgA = pA * 0.08838834764831845f;
    float lgB = pB * 0.08838834764831845f;
    float vfA[8], vfB[8];
    dec8(vA, vfA); dec8(vB, vfB);
    if (lgA > m) {
      float r = __expf(m - lgA);
      s *= r;
#pragma unroll
      for (int i = 0; i < 8; i++) acc[i] *= r;
      m = lgA;
    }
    float wA = __expf(lgA - m);
    s += wA;
#pragma unroll
    for (int i = 0; i < 8; i++) acc[i] += wA * vfA[i];
    if (lgB > m) {
      float r = __expf(m - lgB);
      s *= r;
#pragma unroll
      for (int i = 0; i < 8; i++) acc[i] *= r;
      m = lgB;
    }
    float wB = __expf(lgB - m);
    s += wB;
#pragma unroll
    for (int i = 0; i < 8; i++) acc[i] += wB * vfB[i];
  }
  if (j < j1) {
    int sA = csrc[j];
    uint2 kA = *(const uint2*)(kb + (size_t)sA * 1024);
    uint2 vA = *(const uint2*)(vb + (size_t)sA * 1024);
    float kfA[8], vfA[8];
    dec8(kA, kfA); dec8(vA, vfA);
    float pA = 0.f;
#pragma unroll
    for (int i = 0; i < 8; i++) pA += qf[i] * kfA[i];
    pA += __shfl_xor(pA, 1);
    pA += __shfl_xor(pA, 2);
    pA += __shfl_xor(pA, 4);
    pA += __shfl_xor(pA, 8);
    float lgA = pA * 0.08838834764831845f;
    if (lgA > m) {
      float r = __expf(m - lgA);
      s *= r;
#pragma unroll
      for (int i = 0; i < 8; i++) acc[i] *= r;
      m = lgA;
    }
    float wA = __expf(lgA - m);
    s += wA;
#pragma unroll
    for (int i = 0; i < 8; i++) acc[i] += wA * vfA[i];
  }

  float rsel = 0.25f / (s + 1e-16f);
#pragma unroll
  for (int i = 0; i < 8; i++) {
    float a = acc[i] * rsel;
    a += __shfl_xor(a, 16);
    a += __shfl_xor(a, 32);
    acc[i] = a;
  }

  size_t hbase = (size_t)n * HIDC;
  float u[8];
  {
    float4 h0 = *(const float4*)(h + hbase + t * 8);
    float4 h1 = *(const float4*)(h + hbase + t * 8 + 4);
    float4 k0 = *(const float4*)(skipb + hbase + t * 8);
    float4 k1 = *(const float4*)(skipb + hbase + t * 8 + 4);
    u[0] = h0.x + acc[0] + k0.x; u[1] = h0.y + acc[1] + k0.y;
    u[2] = h0.z + acc[2] + k0.z; u[3] = h0.w + acc[3] + k0.w;
    u[4] = h1.x + acc[4] + k1.x; u[5] = h1.y + acc[5] + k1.y;
    u[6] = h1.z + acc[6] + k1.z; u[7] = h1.w + acc[7] + k1.w;
  }
  float su = 0.f;
#pragma unroll
  for (int i = 0; i < 8; i++) su += u[i];
#pragma unroll
  for (int d = 1; d < 16; d <<= 1) su += __shfl_xor(su, d);
  float mu = su * (1.f / 128.f);
  float vs = 0.f;
#pragma unroll
  for (int i = 0; i < 8; i++) { u[i] -= mu; vs += u[i] * u[i]; }
#pragma unroll
  for (int d = 1; d < 16; d <<= 1) vs += __shfl_xor(vs, d);
  float inv = rsqrtf(vs * (1.f / 128.f) + 1e-5f);
  if (hh == 0) {
    float4 g0 = *(const float4*)(gamma + t * 8);
    float4 g1 = *(const float4*)(gamma + t * 8 + 4);
    float4 b0 = *(const float4*)(beta + t * 8);
    float4 b1 = *(const float4*)(beta + t * 8 + 4);
    float o[8];
    o[0] = u[0] * inv * g0.x + b0.x; o[1] = u[1] * inv * g0.y + b0.y;
    o[2] = u[2] * inv * g0.z + b0.z; o[3] = u[3] * inv * g0.w + b0.w;
    o[4] = u[4] * inv * g1.x + b1.x; o[5] = u[5] * inv * g1.y + b1.y;
    o[6] = u[6] * inv * g1.z + b1.z; o[7] = u[7] * inv * g1.w + b1.w;
    *(float4*)(outp + hbase + t * 8)     = make_float4(o[0], o[1], o[2], o[3]);
    *(float4*)(outp + hbase + t * 8 + 4) = make_float4(o[4], o[5], o[6], o[7]);
    ushort4 c0 = make_ushort4(f2bf(o[0]), f2bf(o[1]), f2bf(o[2]), f2bf(o[3]));
    ushort4 c1 = make_ushort4(f2bf(o[4]), f2bf(o[5]), f2bf(o[6]), f2bf(o[7]));
    *(ushort4*)(hb_out + hbase + t * 8)     = c0;
    *(ushort4*)(hb_out + hbase + t * 8 + 4) = c1;
  }
}

// ---------------- workspace layout (float offsets, all 16B-aligned) ----------------
#define OFF_H      ((size_t)0)            // N*128 fp32
#define OFF_SKIP   ((size_t)2560000)      // N*128 fp32
#define OFF_QB     ((size_t)5120000)      // N*512 bf16
#define OFF_KV8    ((size_t)10240000)     // N*1024 fp8
#define OFF_HB     ((size_t)15360000)     // N*128 bf16
#define OFF_XB     ((size_t)16640000)     // N*64 bf16
#define OFF_WT     ((size_t)17280000)     // 1664*128 bf16
#define OFF_WINT   ((size_t)17386496)     // 128*64 bf16
#define OFF_BCAT   ((size_t)17390592)     // 1664 fp32
#define OFF_CSRC   ((size_t)17392256)     // E ints
#define OFF_ROW    ((size_t)17712256)     // N+1 ints
#define OFF_DEG    ((size_t)17732260)     // N ints
#define OFF_CUR    ((size_t)17752260)     // N ints

extern "C" void kernel_launch(void* const* d_in, const int* in_sizes, int n_in,
                              void* d_out, int out_size, void* d_ws, size_t ws_size,
                              hipStream_t stream) {
  const float* x    = (const float*)d_in[0];
  const int*   ei   = (const int*)d_in[1];
  const float* Win  = (const float*)d_in[2];
  const float* bin_ = (const float*)d_in[3];
  const float* Wq   = (const float*)d_in[4];
  const float* bq   = (const float*)d_in[5];
  const float* Wk   = (const float*)d_in[6];
  const float* bk   = (const float*)d_in[7];
  const float* Wv   = (const float*)d_in[8];
  const float* bv   = (const float*)d_in[9];
  const float* Wsk  = (const float*)d_in[10];
  const float* bsk  = (const float*)d_in[11];
  const float* lng  = (const float*)d_in[12];
  const float* lnb  = (const float*)d_in[13];
  float* out = (float*)d_out;
  float* ws = (float*)d_ws;

  float* h     = ws + OFF_H;
  float* skipb = ws + OFF_SKIP;
  unsigned short* qb   = (unsigned short*)(ws + OFF_QB);
  unsigned char*  kv8  = (unsigned char*)(ws + OFF_KV8);
  unsigned short* hb   = (unsigned short*)(ws + OFF_HB);
  unsigned short* xb   = (unsigned short*)(ws + OFF_XB);
  unsigned short* wT   = (unsigned short*)(ws + OFF_WT);
  unsigned short* winT = (unsigned short*)(ws + OFF_WINT);
  float* bcat  = ws + OFF_BCAT;
  int* csrc     = (int*)(ws + OFF_CSRC);
  int* rowstart = (int*)(ws + OFF_ROW);
  int* deg      = (int*)(ws + OFF_DEG);
  int* cur      = (int*)(ws + OFF_CUR);

  // ---- CSR build ----
  hipMemsetAsync(deg, 0, NN * sizeof(int), stream);
  hipMemsetAsync(cur, 0, NN * sizeof(int), stream);
  deg_hist<<<(EE + 255) / 256, 256, 0, stream>>>(ei, deg);
  scan_deg<<<1, 1024, 0, stream>>>(deg, rowstart);
  csr_scatter<<<(EE + 255) / 256, 256, 0, stream>>>(ei, rowstart, cur, csrc);

  // ---- input projection via MFMA (K=64): h fp32 + hb bf16 ----
  conv_x<<<(NN * DIN / 4 + 255) / 256, 256, 0, stream>>>(x, xb);
  build_winT<<<(HIDC * DIN + 255) / 256, 256, 0, stream>>>(Win, winT);
  {
    const int nby = (NN + 127) / 128;  // 157
    mfma_gemm_t<64, 1><<<nby, 256, 0, stream>>>(xb, winT, bin_, hb, kv8, h, 1, nby);
  }

  for (int l = 0; l < NL; ++l) {
    build_wcatT<<<(NCOLS * HIDC + 255) / 256, 256, 0, stream>>>(
        Wq + (size_t)l * HIDC * 512, Wk + (size_t)l * HIDC * 512,
        Wv + (size_t)l * HIDC * 512, Wsk + (size_t)l * HIDC * HIDC, wT);
    build_bcat<<<(NCOLS + 255) / 256, 256, 0, stream>>>(
        bq + (size_t)l * 512, bk + (size_t)l * 512, bv + (size_t)l * 512,
        bsk + (size_t)l * 128, bcat);

    {
      const int nbx = NCOLS / 128;               // 13
      const int nby = (NN + 127) / 128;          // 157
      const int nwg = nbx * nby;                 // 2041
      mfma_gemm_t<128, 0><<<nwg, 256, 0, stream>>>(hb, wT, bcat, qb, kv8, skipb,
                                                   nbx, nwg);
    }

    float* dst = (l == NL - 1) ? out : h;
    node_fused<<<(NN + 3) / 4, 256, 0, stream>>>(
        qb, kv8, skipb, h, rowstart, csrc,
        lng + (size_t)l * 128, lnb + (size_t)l * 128, dst, hb);
  }
  (void)in_sizes; (void)n_in; (void)out_size; (void)ws_size;
}

// Round 8
// 312.933 us; speedup vs baseline: 14.6025x; 1.0586x over previous
//
#include <hip/hip_runtime.h>
#include <hip/hip_bf16.h>
#include <math.h>

#define NN 20000
#define EE 320000
#define DIN 64
#define HIDC 128
#define NCOLS 1664   // 512 q | 1024 kv(fp8) | 128 skip
#define NL 3

typedef __attribute__((ext_vector_type(8))) short bf16x8;
typedef __attribute__((ext_vector_type(8))) unsigned short u16x8;
typedef __attribute__((ext_vector_type(4))) float f32x4;

__device__ __forceinline__ float bf2f(unsigned short u) {
  union { unsigned i; float f; } v; v.i = ((unsigned)u) << 16; return v.f;
}
__device__ __forceinline__ unsigned short f2bf(float f) {
  __hip_bfloat16 b = __float2bfloat16(f);
  return *(unsigned short*)&b;
}

// ---- fp8 e4m3fn (OCP) encode/decode, HW cvt when available ----
__device__ __forceinline__ unsigned char f2fp8(float f) {
#if __has_builtin(__builtin_amdgcn_cvt_pk_fp8_f32)
  return (unsigned char)(__builtin_amdgcn_cvt_pk_fp8_f32(f, f, 0, 0) & 0xFF);
#else
  unsigned b = __float_as_uint(f);
  unsigned s = (b >> 24) & 0x80u;
  float a = fabsf(f);
  if (a < 0.015625f) return (unsigned char)s;
  unsigned mag = __float_as_uint(fminf(a, 448.f));
  mag += 0x7FFFFu + ((mag >> 20) & 1u);
  unsigned code = (mag >> 20) - (120u << 3);
  if (code > 0x7Eu) code = 0x7Eu;
  return (unsigned char)(s | code);
#endif
}

__device__ __forceinline__ float fp82f(unsigned b) {
  unsigned x = ((b & 0x80u) << 24) | ((b & 0x7fu) << 20);
  return __uint_as_float(x) * 0x1p+120f;
}

__device__ __forceinline__ void dec8(uint2 u, float* f) {
#if __has_builtin(__builtin_amdgcn_cvt_pk_f32_fp8)
  {
    auto p0 = __builtin_amdgcn_cvt_pk_f32_fp8(u.x, 0);
    auto p1 = __builtin_amdgcn_cvt_pk_f32_fp8(u.x, 1);
    auto p2 = __builtin_amdgcn_cvt_pk_f32_fp8(u.y, 0);
    auto p3 = __builtin_amdgcn_cvt_pk_f32_fp8(u.y, 1);
    f[0] = p0[0]; f[1] = p0[1]; f[2] = p1[0]; f[3] = p1[1];
    f[4] = p2[0]; f[5] = p2[1]; f[6] = p3[0]; f[7] = p3[1];
  }
#else
#pragma unroll
  for (int i = 0; i < 4; i++) f[i] = fp82f((u.x >> (8 * i)) & 0xFFu);
#pragma unroll
  for (int i = 0; i < 4; i++) f[4 + i] = fp82f((u.y >> (8 * i)) & 0xFFu);
#endif
}

// ---------------- weight/bias/input prep (all layers at once) ----------------
__global__ void build_wcatT_all(const float* __restrict__ Wq, const float* __restrict__ Wk,
                                const float* __restrict__ Wv, const float* __restrict__ Wsk,
                                unsigned short* __restrict__ wT) {
  int idx = blockIdx.x * 256 + threadIdx.x;
  if (idx >= NL * NCOLS * HIDC) return;
  int l = idx / (NCOLS * HIDC);
  int rem = idx - l * (NCOLS * HIDC);
  int n = rem >> 7, k = rem & 127;
  float v;
  if (n < 512)       v = Wq[(size_t)l * HIDC * 512 + (size_t)k * 512 + n];
  else if (n < 1024) v = Wk[(size_t)l * HIDC * 512 + (size_t)k * 512 + (n - 512)];
  else if (n < 1536) v = Wv[(size_t)l * HIDC * 512 + (size_t)k * 512 + (n - 1024)];
  else               v = Wsk[(size_t)l * HIDC * HIDC + (size_t)k * 128 + (n - 1536)];
  wT[idx] = f2bf(v);
}

__global__ void build_bcat_all(const float* __restrict__ bq, const float* __restrict__ bk,
                               const float* __restrict__ bv, const float* __restrict__ bsk,
                               float* __restrict__ bcat) {
  int idx = blockIdx.x * 256 + threadIdx.x;
  if (idx >= NL * NCOLS) return;
  int l = idx / NCOLS, m = idx - l * NCOLS;
  float v;
  if (m < 512)       v = bq[l * 512 + m];
  else if (m < 1024) v = bk[l * 512 + (m - 512)];
  else if (m < 1536) v = bv[l * 512 + (m - 1024)];
  else               v = bsk[l * 128 + (m - 1536)];
  bcat[idx] = v;
}

__global__ void build_winT(const float* __restrict__ Win, unsigned short* __restrict__ winT) {
  int idx = blockIdx.x * 256 + threadIdx.x;
  if (idx >= HIDC * DIN) return;
  int c = idx >> 6, k = idx & 63;
  winT[idx] = f2bf(Win[(size_t)k * HIDC + c]);
}

__global__ void conv_x(const float* __restrict__ x, unsigned short* __restrict__ xb) {
  int i = blockIdx.x * 256 + threadIdx.x;
  if (i * 4 >= NN * DIN) return;
  float4 v = *(const float4*)(x + (size_t)i * 4);
  ushort4 o = make_ushort4(f2bf(v.x), f2bf(v.y), f2bf(v.z), f2bf(v.w));
  *(ushort4*)(xb + (size_t)i * 4) = o;
}

// ---------------- CSR build ----------------
__global__ void deg_hist(const int* __restrict__ ei, int* __restrict__ deg) {
  int e = blockIdx.x * 256 + threadIdx.x;
  if (e >= EE) return;
  atomicAdd(&deg[ei[EE + e]], 1);
}

__global__ __launch_bounds__(1024) void scan_deg(const int* __restrict__ deg,
                                                 int* __restrict__ rowstart) {
  __shared__ int part[1024];
  int t = threadIdx.x;
  int base = t * 20;
  int local[20];
  int s = 0;
#pragma unroll
  for (int i = 0; i < 20; i++) {
    int idx = base + i;
    int d = (idx < NN) ? deg[idx] : 0;
    local[i] = d;
    s += d;
  }
  part[t] = s;
  __syncthreads();
  for (int d = 1; d < 1024; d <<= 1) {
    int v = (t >= d) ? part[t - d] : 0;
    __syncthreads();
    part[t] += v;
    __syncthreads();
  }
  int run = part[t] - s;
#pragma unroll
  for (int i = 0; i < 20; i++) {
    int idx = base + i;
    if (idx < NN) rowstart[idx] = run;
    run += local[i];
  }
  if (t == 1023) rowstart[NN] = part[1023];
}

__global__ void csr_scatter(const int* __restrict__ ei, const int* __restrict__ rowstart,
                            int* __restrict__ cur, int* __restrict__ csrc) {
  int e = blockIdx.x * 256 + threadIdx.x;
  if (e >= EE) return;
  int src = ei[e], dst = ei[EE + e];
  int pos = atomicAdd(&cur[dst], 1);
  csrc[rowstart[dst] + pos] = src;
}

// ---------------- MFMA helpers ----------------
__device__ __forceinline__ void gl_lds16(const void* g, void* l) {
  __builtin_amdgcn_global_load_lds((const unsigned int*)g, (unsigned int*)l, 16, 0, 0);
}

template <int K>
__device__ __forceinline__ void stage_tile(const unsigned short* gbase,
                                           unsigned char* lbase, int tid) {
  constexpr int CH = K / 8;
  constexpr int ISS = (128 * CH) / 256;
  int wave = tid >> 6;
#pragma unroll
  for (int p = 0; p < ISS; p++) {
    int slot = p * 256 + tid;
    int row = slot / CH, ch = slot % CH;
    const unsigned short* src = gbase + (size_t)row * K + ((ch ^ (row & 7)) * 8);
    unsigned char* ldst = lbase + (size_t)(p * 256 + wave * 64) * 16;
    gl_lds16(src, ldst);
  }
}

template <int K>
__device__ __forceinline__ bf16x8 read_frag(const unsigned char* lbase, int row, int kk, int lk) {
  int ch = (kk * 4 + lk) ^ (row & 7);
  return *(const bf16x8*)(lbase + (size_t)row * (K * 2) + ch * 16);
}

// ---------------- input-projection GEMM (128x128 tile, K=64) ----------------
__global__ __launch_bounds__(256) void mfma_gemm_in(
    const unsigned short* __restrict__ A, const unsigned short* __restrict__ BT,
    const float* __restrict__ bias, unsigned short* __restrict__ outb,
    float* __restrict__ outf) {
  __shared__ __align__(16) unsigned char LDS[34816];
  const int tid = threadIdx.x;
  const int lane = tid & 63, wave = tid >> 6;
  const int lm = lane & 15, lk = lane >> 4;
  const int wm = wave >> 1, wn = wave & 1;
  const int row0 = blockIdx.x * 128, col0 = 0;
  unsigned char* aL = LDS;
  unsigned char* bL = LDS + 128 * 64 * 2;

  stage_tile<64>(A + (size_t)row0 * 64, aL, tid);
  stage_tile<64>(BT + (size_t)col0 * 64, bL, tid);
  __syncthreads();

  f32x4 acc[4][4] = {};
  bf16x8 af[4][2];
#pragma unroll
  for (int mf = 0; mf < 4; mf++)
#pragma unroll
    for (int kk = 0; kk < 2; kk++)
      af[mf][kk] = read_frag<64>(aL, wm * 64 + mf * 16 + lm, kk, lk);
#pragma unroll
  for (int nf = 0; nf < 4; nf++) {
    bf16x8 bf[2];
#pragma unroll
    for (int kk = 0; kk < 2; kk++)
      bf[kk] = read_frag<64>(bL, wn * 64 + nf * 16 + lm, kk, lk);
#pragma unroll
    for (int mf = 0; mf < 4; mf++)
#pragma unroll
      for (int kk = 0; kk < 2; kk++)
        acc[mf][nf] = __builtin_amdgcn_mfma_f32_16x16x32_bf16(af[mf][kk], bf[kk],
                                                              acc[mf][nf], 0, 0, 0);
  }
  __syncthreads();

  unsigned short* bb = (unsigned short*)LDS;
#pragma unroll
  for (int nf = 0; nf < 4; nf++) {
    int c = wn * 64 + nf * 16 + lm;
    float bv = bias[c];
#pragma unroll
    for (int mf = 0; mf < 4; mf++)
#pragma unroll
      for (int i = 0; i < 4; i++) {
        int row = wm * 64 + mf * 16 + lk * 4 + i;
        float o = acc[mf][nf][i] + bv;
        bb[row * 136 + c] = f2bf(o);
        int r = row0 + row;
        if (r < NN) outf[(size_t)r * HIDC + c] = o;
      }
  }
  __syncthreads();
#pragma unroll
  for (int p = 0; p < 8; p++) {
    int idx = p * 256 + tid;
    int row = idx >> 4, c = idx & 15;
    int gr = row0 + row;
    if (gr < NN) {
      uint4 v = *(const uint4*)(bb + row * 136 + c * 8);
      *(uint4*)(outb + (size_t)gr * HIDC + c * 8) = v;
    }
  }
}

// ---------------- layer GEMM: 64x64 tiles, 32KB LDS, 5 blocks/CU ----------------
// cols: bx 0-7 -> q bf16 | bx 8-23 -> kv fp8 | bx 24-25 -> skip fp32
__global__ __launch_bounds__(256, 5) void gemm64(
    const unsigned short* __restrict__ A, const unsigned short* __restrict__ BT,
    const float* __restrict__ bias, unsigned short* __restrict__ qb,
    unsigned char* __restrict__ kv8, float* __restrict__ skipb,
    int nbx, int nwg) {
  __shared__ __align__(16) unsigned char LDS[32768];
  const int tid = threadIdx.x;
  // bijective XCD-chunk swizzle; bx fastest -> A-tile reuse within XCD chunk
  int orig = blockIdx.x;
  int qq = nwg >> 3, rr8 = nwg & 7;
  int xcd = orig & 7, slot = orig >> 3;
  int wg = (xcd < rr8 ? xcd * (qq + 1) : rr8 * (qq + 1) + (xcd - rr8) * qq) + slot;
  const int bx = wg % nbx, by = wg / nbx;

  const int lane = tid & 63, wave = tid >> 6;
  const int lm = lane & 15, lk = lane >> 4;
  const int wm = wave >> 1, wn = wave & 1;
  const int row0 = by * 64, col0 = bx * 64;
  unsigned char* aL = LDS;
  unsigned char* bL = LDS + 16384;

  // stage A,B: 64 rows x 16 chunks each
  {
    const unsigned short* gA = A + (size_t)row0 * 128;
    const unsigned short* gB = BT + (size_t)col0 * 128;
#pragma unroll
    for (int p = 0; p < 4; p++) {
      int sl = p * 256 + tid;
      int row = sl >> 4, ch = sl & 15;
      gl_lds16(gA + (size_t)row * 128 + ((ch ^ (row & 7)) * 8),
               aL + (size_t)(p * 256 + wave * 64) * 16);
    }
#pragma unroll
    for (int p = 0; p < 4; p++) {
      int sl = p * 256 + tid;
      int row = sl >> 4, ch = sl & 15;
      gl_lds16(gB + (size_t)row * 128 + ((ch ^ (row & 7)) * 8),
               bL + (size_t)(p * 256 + wave * 64) * 16);
    }
  }
  __syncthreads();

  f32x4 acc[2][2] = {};
  bf16x8 af[2][4], bf[2][4];
#pragma unroll
  for (int mf = 0; mf < 2; mf++)
#pragma unroll
    for (int kk = 0; kk < 4; kk++)
      af[mf][kk] = read_frag<128>(aL, wm * 32 + mf * 16 + lm, kk, lk);
#pragma unroll
  for (int nf = 0; nf < 2; nf++)
#pragma unroll
    for (int kk = 0; kk < 4; kk++)
      bf[nf][kk] = read_frag<128>(bL, wn * 32 + nf * 16 + lm, kk, lk);
#pragma unroll
  for (int nf = 0; nf < 2; nf++)
#pragma unroll
    for (int mf = 0; mf < 2; mf++)
#pragma unroll
      for (int kk = 0; kk < 4; kk++)
        acc[mf][nf] = __builtin_amdgcn_mfma_f32_16x16x32_bf16(af[mf][kk], bf[nf][kk],
                                                              acc[mf][nf], 0, 0, 0);
  __syncthreads();  // all LDS frag reads done -> safe to reuse LDS for bounce

  if (bx >= 24) {
    // skip: fp32 direct (16 lanes x 4B = 64B contiguous per row)
    const int cbase = col0 - 1536;
#pragma unroll
    for (int nf = 0; nf < 2; nf++) {
      int c = wn * 32 + nf * 16 + lm;
      float bv = bias[col0 + c];
#pragma unroll
      for (int mf = 0; mf < 2; mf++)
#pragma unroll
        for (int i = 0; i < 4; i++) {
          int r = row0 + wm * 32 + mf * 16 + lk * 4 + i;
          if (r < NN) skipb[(size_t)r * HIDC + cbase + c] = acc[mf][nf][i] + bv;
        }
    }
  } else if (bx >= 8) {
    // kv fp8 bounce: [64][80] bytes (80 = 16*5, aligned rows)
    unsigned char* bb8 = LDS;
#pragma unroll
    for (int nf = 0; nf < 2; nf++) {
      int c = wn * 32 + nf * 16 + lm;
      float bv = bias[col0 + c];
#pragma unroll
      for (int mf = 0; mf < 2; mf++)
#pragma unroll
        for (int i = 0; i < 4; i++) {
          int row = wm * 32 + mf * 16 + lk * 4 + i;
          bb8[row * 80 + c] = f2fp8(acc[mf][nf][i] + bv);
        }
    }
    __syncthreads();
    const int kvcol0 = col0 - 512;
    {
      int row = tid >> 2, cw = tid & 3;
      int gr = row0 + row;
      if (gr < NN) {
        uint4 v = *(const uint4*)(bb8 + row * 80 + cw * 16);
        *(uint4*)(kv8 + (size_t)gr * 1024 + kvcol0 + cw * 16) = v;
      }
    }
  } else {
    // q bf16 bounce: [64][80] shorts (160B rows, aligned)
    unsigned short* bb = (unsigned short*)LDS;
#pragma unroll
    for (int nf = 0; nf < 2; nf++) {
      int c = wn * 32 + nf * 16 + lm;
      float bv = bias[col0 + c];
#pragma unroll
      for (int mf = 0; mf < 2; mf++)
#pragma unroll
        for (int i = 0; i < 4; i++) {
          int row = wm * 32 + mf * 16 + lk * 4 + i;
          bb[row * 80 + c] = f2bf(acc[mf][nf][i] + bv);
        }
    }
    __syncthreads();
#pragma unroll
    for (int p = 0; p < 2; p++) {
      int idx = p * 256 + tid;
      int row = idx >> 3, cw = idx & 7;
      int gr = row0 + row;
      if (gr < NN) {
        uint4 v = *(const uint4*)(bb + row * 80 + cw * 8);
        *(uint4*)(qb + (size_t)gr * 512 + col0 + cw * 8) = v;
      }
    }
  }
}

// ---------------- fused single-pass flash-style node kernel (fp8 k/v) ----------------
__global__ __launch_bounds__(256) void node_fused(
    const unsigned short* __restrict__ qb, const unsigned char* __restrict__ kv8,
    const float* __restrict__ skipb,
    const float* __restrict__ h, const int* __restrict__ rowstart,
    const int* __restrict__ csrc,
    const float* __restrict__ gamma, const float* __restrict__ beta,
    float* __restrict__ outp, unsigned short* __restrict__ hb_out) {
  int n = blockIdx.x * 4 + (threadIdx.x >> 6);
  if (n >= NN) return;
  int lane = threadIdx.x & 63;
  int hh = lane >> 4, t = lane & 15;
  int j0 = rowstart[n], j1 = rowstart[n + 1];

  u16x8 q8 = *(const u16x8*)(qb + (size_t)n * 512 + hh * 128 + t * 8);
  float qf[8];
#pragma unroll
  for (int i = 0; i < 8; i++) qf[i] = bf2f(q8[i]);

  const unsigned char* kb = kv8 + hh * 128 + t * 8;
  const unsigned char* vb = kv8 + 512 + hh * 128 + t * 8;

  float m = -INFINITY, s = 0.f;
  float acc[8] = {0.f, 0.f, 0.f, 0.f, 0.f, 0.f, 0.f, 0.f};

  int j = j0;
  // 4-edge unrolled main loop: all 8 gathers issued before any use
  for (; j + 3 < j1; j += 4) {
    int s4[4];
#pragma unroll
    for (int e = 0; e < 4; e++) s4[e] = csrc[j + e];
    uint2 kk4[4], vv4[4];
#pragma unroll
    for (int e = 0; e < 4; e++) {
      kk4[e] = *(const uint2*)(kb + (size_t)s4[e] * 1024);
      vv4[e] = *(const uint2*)(vb + (size_t)s4[e] * 1024);
    }
    float lg4[4];
#pragma unroll
    for (int e = 0; e < 4; e++) {
      float kf[8];
      dec8(kk4[e], kf);
      float p = 0.f;
#pragma unroll
      for (int i = 0; i < 8; i++) p += qf[i] * kf[i];
      p += __shfl_xor(p, 1);
      p += __shfl_xor(p, 2);
      p += __shfl_xor(p, 4);
      p += __shfl_xor(p, 8);
      lg4[e] = p * 0.08838834764831845f;
    }
    float mx = fmaxf(fmaxf(lg4[0], lg4[1]), fmaxf(lg4[2], lg4[3]));
    if (mx > m) {
      float rr = __expf(m - mx);  // exp(-inf)=0 bootstraps first group
      s *= rr;
#pragma unroll
      for (int i = 0; i < 8; i++) acc[i] *= rr;
      m = mx;
    }
#pragma unroll
    for (int e = 0; e < 4; e++) {
      float w = __expf(lg4[e] - m);
      s += w;
      float vf[8];
      dec8(vv4[e], vf);
#pragma unroll
      for (int i = 0; i < 8; i++) acc[i] += w * vf[i];
    }
  }
  // remainder
  for (; j < j1; ++j) {
    int sA = csrc[j];
    uint2 kA = *(const uint2*)(kb + (size_t)sA * 1024);
    uint2 vA = *(const uint2*)(vb + (size_t)sA * 1024);
    float kfA[8], vfA[8];
    dec8(kA, kfA); dec8(vA, vfA);
    float pA = 0.f;
#pragma unroll
    for (int i = 0; i < 8; i++) pA += qf[i] * kfA[i];
    pA += __shfl_xor(pA, 1);
    pA += __shfl_xor(pA, 2);
    pA += __shfl_xor(pA, 4);
    pA += __shfl_xor(pA, 8);
    float lgA = pA * 0.08838834764831845f;
    if (lgA > m) {
      float rr = __expf(m - lgA);
      s *= rr;
#pragma unroll
      for (int i = 0; i < 8; i++) acc[i] *= rr;
      m = lgA;
    }
    float wA = __expf(lgA - m);
    s += wA;
#pragma unroll
    for (int i = 0; i < 8; i++) acc[i] += wA * vfA[i];
  }

  float rsel = 0.25f / (s + 1e-16f);
#pragma unroll
  for (int i = 0; i < 8; i++) {
    float a = acc[i] * rsel;
    a += __shfl_xor(a, 16);
    a += __shfl_xor(a, 32);
    acc[i] = a;
  }

  size_t hbase = (size_t)n * HIDC;
  float u[8];
  {
    float4 h0 = *(const float4*)(h + hbase + t * 8);
    float4 h1 = *(const float4*)(h + hbase + t * 8 + 4);
    float4 k0 = *(const float4*)(skipb + hbase + t * 8);
    float4 k1 = *(const float4*)(skipb + hbase + t * 8 + 4);
    u[0] = h0.x + acc[0] + k0.x; u[1] = h0.y + acc[1] + k0.y;
    u[2] = h0.z + acc[2] + k0.z; u[3] = h0.w + acc[3] + k0.w;
    u[4] = h1.x + acc[4] + k1.x; u[5] = h1.y + acc[5] + k1.y;
    u[6] = h1.z + acc[6] + k1.z; u[7] = h1.w + acc[7] + k1.w;
  }
  float su = 0.f;
#pragma unroll
  for (int i = 0; i < 8; i++) su += u[i];
#pragma unroll
  for (int d = 1; d < 16; d <<= 1) su += __shfl_xor(su, d);
  float mu = su * (1.f / 128.f);
  float vs = 0.f;
#pragma unroll
  for (int i = 0; i < 8; i++) { u[i] -= mu; vs += u[i] * u[i]; }
#pragma unroll
  for (int d = 1; d < 16; d <<= 1) vs += __shfl_xor(vs, d);
  float inv = rsqrtf(vs * (1.f / 128.f) + 1e-5f);
  if (hh == 0) {
    float4 g0 = *(const float4*)(gamma + t * 8);
    float4 g1 = *(const float4*)(gamma + t * 8 + 4);
    float4 b0 = *(const float4*)(beta + t * 8);
    float4 b1 = *(const float4*)(beta + t * 8 + 4);
    float o[8];
    o[0] = u[0] * inv * g0.x + b0.x; o[1] = u[1] * inv * g0.y + b0.y;
    o[2] = u[2] * inv * g0.z + b0.z; o[3] = u[3] * inv * g0.w + b0.w;
    o[4] = u[4] * inv * g1.x + b1.x; o[5] = u[5] * inv * g1.y + b1.y;
    o[6] = u[6] * inv * g1.z + b1.z; o[7] = u[7] * inv * g1.w + b1.w;
    *(float4*)(outp + hbase + t * 8)     = make_float4(o[0], o[1], o[2], o[3]);
    *(float4*)(outp + hbase + t * 8 + 4) = make_float4(o[4], o[5], o[6], o[7]);
    ushort4 c0 = make_ushort4(f2bf(o[0]), f2bf(o[1]), f2bf(o[2]), f2bf(o[3]));
    ushort4 c1 = make_ushort4(f2bf(o[4]), f2bf(o[5]), f2bf(o[6]), f2bf(o[7]));
    *(ushort4*)(hb_out + hbase + t * 8)     = c0;
    *(ushort4*)(hb_out + hbase + t * 8 + 4) = c1;
  }
}

// ---------------- workspace layout (float offsets, all 16B-aligned) ----------------
#define OFF_H      ((size_t)0)            // N*128 fp32
#define OFF_SKIP   ((size_t)2560000)      // N*128 fp32
#define OFF_QB     ((size_t)5120000)      // N*512 bf16
#define OFF_KV8    ((size_t)10240000)     // N*1024 fp8
#define OFF_HB     ((size_t)15360000)     // N*128 bf16
#define OFF_XB     ((size_t)16640000)     // N*64 bf16
#define OFF_WT     ((size_t)17280000)     // 3*1664*128 bf16 = 319488 floats
#define OFF_WINT   ((size_t)17599488)     // 128*64 bf16
#define OFF_BCAT   ((size_t)17603584)     // 3*1664 fp32
#define OFF_CSRC   ((size_t)17608576)     // E ints
#define OFF_ROW    ((size_t)17928576)     // N+1 ints
#define OFF_DEG    ((size_t)17948580)     // N ints
#define OFF_CUR    ((size_t)17968580)     // N ints
// end ~17.99M floats ~= 72 MB

extern "C" void kernel_launch(void* const* d_in, const int* in_sizes, int n_in,
                              void* d_out, int out_size, void* d_ws, size_t ws_size,
                              hipStream_t stream) {
  const float* x    = (const float*)d_in[0];
  const int*   ei   = (const int*)d_in[1];
  const float* Win  = (const float*)d_in[2];
  const float* bin_ = (const float*)d_in[3];
  const float* Wq   = (const float*)d_in[4];
  const float* bq   = (const float*)d_in[5];
  const float* Wk   = (const float*)d_in[6];
  const float* bk   = (const float*)d_in[7];
  const float* Wv   = (const float*)d_in[8];
  const float* bv   = (const float*)d_in[9];
  const float* Wsk  = (const float*)d_in[10];
  const float* bsk  = (const float*)d_in[11];
  const float* lng  = (const float*)d_in[12];
  const float* lnb  = (const float*)d_in[13];
  float* out = (float*)d_out;
  float* ws = (float*)d_ws;

  float* h     = ws + OFF_H;
  float* skipb = ws + OFF_SKIP;
  unsigned short* qb   = (unsigned short*)(ws + OFF_QB);
  unsigned char*  kv8  = (unsigned char*)(ws + OFF_KV8);
  unsigned short* hb   = (unsigned short*)(ws + OFF_HB);
  unsigned short* xb   = (unsigned short*)(ws + OFF_XB);
  unsigned short* wT   = (unsigned short*)(ws + OFF_WT);
  unsigned short* winT = (unsigned short*)(ws + OFF_WINT);
  float* bcat  = ws + OFF_BCAT;
  int* csrc     = (int*)(ws + OFF_CSRC);
  int* rowstart = (int*)(ws + OFF_ROW);
  int* deg      = (int*)(ws + OFF_DEG);
  int* cur      = (int*)(ws + OFF_CUR);

  // ---- CSR build + all-layer weight prep (independent, front-loaded) ----
  hipMemsetAsync(deg, 0, NN * sizeof(int), stream);
  hipMemsetAsync(cur, 0, NN * sizeof(int), stream);
  deg_hist<<<(EE + 255) / 256, 256, 0, stream>>>(ei, deg);
  scan_deg<<<1, 1024, 0, stream>>>(deg, rowstart);
  csr_scatter<<<(EE + 255) / 256, 256, 0, stream>>>(ei, rowstart, cur, csrc);

  conv_x<<<(NN * DIN / 4 + 255) / 256, 256, 0, stream>>>(x, xb);
  build_winT<<<(HIDC * DIN + 255) / 256, 256, 0, stream>>>(Win, winT);
  build_wcatT_all<<<(NL * NCOLS * HIDC + 255) / 256, 256, 0, stream>>>(
      Wq, Wk, Wv, Wsk, wT);
  build_bcat_all<<<(NL * NCOLS + 255) / 256, 256, 0, stream>>>(bq, bk, bv, bsk, bcat);

  // ---- input projection via MFMA (K=64): h fp32 + hb bf16 ----
  mfma_gemm_in<<<(NN + 127) / 128, 256, 0, stream>>>(xb, winT, bin_, hb, h);

  const int nbx = NCOLS / 64;            // 26
  const int nby = (NN + 63) / 64;        // 313
  const int nwg = nbx * nby;             // 8138

  for (int l = 0; l < NL; ++l) {
    gemm64<<<nwg, 256, 0, stream>>>(hb, wT + (size_t)l * NCOLS * HIDC,
                                    bcat + (size_t)l * NCOLS, qb, kv8, skipb,
                                    nbx, nwg);

    float* dst = (l == NL - 1) ? out : h;
    node_fused<<<(NN + 3) / 4, 256, 0, stream>>>(
        qb, kv8, skipb, h, rowstart, csrc,
        lng + (size_t)l * 128, lnb + (size_t)l * 128, dst, hb);
  }
  (void)in_sizes; (void)n_in; (void)out_size; (void)ws_size;
}